// Round 7
// baseline (409.553 us; speedup 1.0000x reference)
//
#include <hip/hip_runtime.h>

#define NU 100000
#define NI 50000
#define NN 150000   // NU + NI
#define D  64
#define CAP 47      // bucket capacity per dst; max in-degree ~44 for Poisson(21.3)
#define OVF_MAX 4096

// binning params (256-wide bins: regroup block reads exactly its own records)
#define BINSHIFT 8
#define BINW 256                 // dsts per bin
#define NBINS 586                // ceil(150000/256); 586*256 = 150016
#define BINCAP 5848              // per-bin record cap, mult of 8
#define STAGE_CAP 11             // LDS stage slots per bin (53.9KB -> 3 blocks/CU)
#define EPT 4                    // edges per thread per batch
#define SPILL_CAP 262144
#define BIN_BLOCKS 768           // 256 CUs x 3 blocks/CU, one round
#define BCPAD 16                 // bincur stride: 1 word per 64B cacheline
                                 // (R6-verified: removed k_bin's 75us atomic
                                 //  line-contention stall)

typedef unsigned int uint;
typedef unsigned short ushort;
typedef unsigned char uchar;

// ---------------- helpers ----------------
__device__ __forceinline__ float half_reduce_add(float v) {  // reduce within 32-lane half
    #pragma unroll
    for (int m = 16; m >= 1; m >>= 1) v += __shfl_xor(v, m, 64);
    return v;
}
__device__ __forceinline__ ushort f2bf(float f) {   // round-to-nearest-even
    union { float f; uint i; } c; c.f = f;
    uint r = c.i + 0x7FFF + ((c.i >> 16) & 1);
    return (ushort)(r >> 16);
}
__device__ __forceinline__ float lane_bcast(float v, int l) {
    return __int_as_float(__builtin_amdgcn_readlane(__float_as_int(v), l));
}
// bf14 weight encoding: rounded top-14 bits of f32 (w in [0,1)); decode = 1 AND
__device__ __forceinline__ uint enc14(float w) {
    uint b = __float_as_uint(w) + 0x00020000u;   // round at bit 18
    return b & 0xFFFC0000u;
}
__device__ __forceinline__ float dec14(uint r) {
    return __uint_as_float(r & 0xFFFC0000u);
}
__device__ __forceinline__ void spill_one(int d, uint s, float w,
        uint2* __restrict__ spill, int* __restrict__ spillcnt) {
    int si = atomicAdd(spillcnt, 1);
    if (si < SPILL_CAP) spill[si] = make_uint2(s | enc14(w), (uint)d);
}

// ---------------- pass 1: LDS-staged binning, line-coalesced flushes ----------
__global__ __launch_bounds__(256) void k_bin(
        const int* __restrict__ src, const int* __restrict__ dst,
        const float* __restrict__ ew, int* __restrict__ bincur,
        uint2* __restrict__ binbuf, uint2* __restrict__ spill,
        int* __restrict__ spillcnt, uint2* __restrict__ tail,
        uchar* __restrict__ cnt8, int E) {
    __shared__ uint2 stage[NBINS][STAGE_CAP];   // 51.6 KB -> 3 blocks/CU
    __shared__ int scnt[NBINS];
    int t = threadIdx.x;
    for (int i = t; i < NBINS; i += 256) scnt[i] = 0;
    __syncthreads();
    const int batch = 256 * EPT;
    for (int base = blockIdx.x * batch; base < E; base += BIN_BLOCKS * batch) {
        int dd[EPT]; uint ss[EPT]; float ww[EPT]; int ok[EPT];
        #pragma unroll
        for (int k = 0; k < EPT; ++k) {
            int e = base + k * 256 + t;
            ok[k] = (e < E);
            if (ok[k]) { dd[k] = dst[e]; ss[k] = (uint)src[e]; ww[k] = ew[e]; }
        }
        #pragma unroll
        for (int k = 0; k < EPT; ++k) {
            if (!ok[k]) continue;
            int bin = dd[k] >> BINSHIFT;
            int slot = atomicAdd(&scnt[bin], 1);
            if (slot < STAGE_CAP) {
                stage[bin][slot] = make_uint2(
                    ss[k] | ((uint)(dd[k] & (BINW - 1)) << 18),
                    (uint)__float_as_int(ww[k]));
            } else {
                spill_one(dd[k], ss[k], ww[k], spill, spillcnt);  // rare
            }
        }
        __syncthreads();
        for (int bin = t; bin < NBINS; bin += 256) {
            int c = scnt[bin]; if (c > STAGE_CAP) c = STAGE_CAP;
            while (c >= 8) {                // takes TOP 8, leaves bottom c-8
                int b0 = atomicAdd(&bincur[bin * BCPAD], 8);
                if (b0 + 8 <= BINCAP) {
                    uint4* o4 = (uint4*)(binbuf + (size_t)bin * BINCAP + b0);
                    uint2* s2 = &stage[bin][c - 8];
                    o4[0] = make_uint4(s2[0].x, s2[0].y, s2[1].x, s2[1].y);
                    o4[1] = make_uint4(s2[2].x, s2[2].y, s2[3].x, s2[3].y);
                    o4[2] = make_uint4(s2[4].x, s2[4].y, s2[5].x, s2[5].y);
                    o4[3] = make_uint4(s2[6].x, s2[6].y, s2[7].x, s2[7].y);
                } else {
                    for (int j = 0; j < 8; ++j) {
                        uint2 r = stage[bin][c - 8 + j];
                        spill_one((bin << BINSHIFT) + (int)(r.x >> 18),
                                  r.x & 0x3FFFFu, __int_as_float((int)r.y),
                                  spill, spillcnt);
                    }
                }
                c -= 8;
            }
            scnt[bin] = c;
        }
        __syncthreads();
    }
    // final residuals: c <= 7 per bin, in stage slots [0, c). Coalesced dump.
    uchar* cb = cnt8 + (size_t)blockIdx.x * NBINS;
    for (int i = t; i < NBINS; i += 256) cb[i] = (uchar)scnt[i];
    uint2* tb = tail + (size_t)blockIdx.x * (NBINS * 8);
    for (int i = t; i < NBINS * 8; i += 256) tb[i] = stage[i >> 3][i & 7];
}

// -------- pass 2: regroup + tails + spills + weighted degree + dinv -----------
__global__ __launch_bounds__(256) void k_regroup(
        const int* __restrict__ bincur, const uint2* __restrict__ binbuf,
        const uint2* __restrict__ spill, const int* __restrict__ spillcnt,
        const uint2* __restrict__ tail, const uchar* __restrict__ cnt8,
        uint* __restrict__ recs, int* __restrict__ cursor,
        float* __restrict__ dinv, int4* __restrict__ ovf,
        int* __restrict__ ovfcnt) {
    __shared__ uint image[256 * CAP];   // 47 KB, layout == recs layout
    __shared__ int cnt[256];
    __shared__ float ovfw[256];
    int t = threadIdx.x;
    int bin = blockIdx.x;
    cnt[t] = 0; ovfw[t] = 0.0f;
    __syncthreads();
    int dbase = bin << BINSHIFT;
    int nrec = bincur[bin * BCPAD]; if (nrec > BINCAP) nrec = BINCAP;
    const uint2* bb = binbuf + (size_t)bin * BINCAP;
    for (int i = t; i < nrec; i += 256) {
        uint2 r = bb[i];
        int dl = (int)(r.x >> 18);          // 8-bit dlocal, top bits zero
        int slot = atomicAdd(&cnt[dl], 1);
        uint s = r.x & 0x3FFFFu;
        float w = __int_as_float((int)r.y);
        if (slot < CAP) image[dl * CAP + slot] = enc14(w) | s;
        else {                                              // rare high-degree
            atomicAdd(&ovfw[dl], w);
            int o = atomicAdd(ovfcnt, 1);
            if (o < OVF_MAX)
                ovf[o] = make_int4(dbase + dl, (int)s, __float_as_int(w), 0);
        }
    }
    // per-block residual tails for this bin (~half of all records)
    for (int g = t; g < BIN_BLOCKS; g += 256) {
        int c = cnt8[(size_t)g * NBINS + bin];
        const uint2* tb = tail + ((size_t)g * NBINS + bin) * 8;
        for (int j = 0; j < c; ++j) {
            uint2 r = tb[j];
            int dl = (int)(r.x >> 18);
            int slot = atomicAdd(&cnt[dl], 1);
            uint s = r.x & 0x3FFFFu;
            float w = __int_as_float((int)r.y);
            if (slot < CAP) image[dl * CAP + slot] = enc14(w) | s;
            else {
                atomicAdd(&ovfw[dl], w);
                int o = atomicAdd(ovfcnt, 1);
                if (o < OVF_MAX)
                    ovf[o] = make_int4(dbase + dl, (int)s, __float_as_int(w), 0);
            }
        }
    }
    // spill entries (rare); spill words already bf14-encoded
    int ns = spillcnt[0]; if (ns > SPILL_CAP) ns = SPILL_CAP;
    for (int i = t; i < ns; i += 256) {
        uint2 e = spill[i];
        int d = (int)e.y;
        if (d < dbase || d >= dbase + BINW) continue;
        int dl = d - dbase;
        int slot = atomicAdd(&cnt[dl], 1);
        if (slot < CAP) image[dl * CAP + slot] = e.x;
        else {
            float w = dec14(e.x);
            atomicAdd(&ovfw[dl], w);
            int o = atomicAdd(ovfcnt, 1);
            if (o < OVF_MAX) ovf[o] = make_int4(d, (int)(e.x & 0x3FFFFu),
                                                __float_as_int(w), 0);
        }
    }
    __syncthreads();
    int ndl = NN - dbase; if (ndl > 256) ndl = 256;
    if (ndl <= 0) return;
    if (t < ndl) {
        int c = cnt[t];
        cursor[dbase + t] = c;
        if (c > CAP) c = CAP;
        float dg = ovfw[t];
        for (int j = 0; j < c; ++j) dg += dec14(image[t * CAP + j]);
        dinv[dbase + t] = rsqrtf(dg + 1.0f);   // self-loop weight 1 folded in
    }
    int tot = ndl * CAP;
    uint* out = recs + (size_t)dbase * CAP;
    for (int i = t; i < tot; i += 256) out[i] = image[i];  // fully coalesced
}

// ------- layer-1 GEMM: hw2b = bf16((x @ W0) * dinv), x = [U;I] f32 -----------
__global__ __launch_bounds__(256) void k_gemm1(
        const float* __restrict__ U, const float* __restrict__ I,
        const float* __restrict__ W, const float* __restrict__ dinv,
        ushort* __restrict__ out) {
    int lane = threadIdx.x & 63;
    float wreg[64];                         // column `lane` of W0
    #pragma unroll
    for (int k = 0; k < 64; ++k) wreg[k] = W[k * 64 + lane];
    int wpb = blockDim.x >> 6;
    int wid = blockIdx.x * wpb + (threadIdx.x >> 6);
    int tw = gridDim.x * wpb;
    for (int n = wid; n < NN; n += tw) {
        float xv = (n < NU) ? U[(size_t)n * D + lane]
                            : I[(size_t)(n - NU) * D + lane];
        float a0 = 0.f, a1 = 0.f, a2 = 0.f, a3 = 0.f;  // 4 chains (ILP)
        #pragma unroll
        for (int k = 0; k < 64; k += 4) {
            a0 = fmaf(lane_bcast(xv, k + 0), wreg[k + 0], a0);
            a1 = fmaf(lane_bcast(xv, k + 1), wreg[k + 1], a1);
            a2 = fmaf(lane_bcast(xv, k + 2), wreg[k + 2], a2);
            a3 = fmaf(lane_bcast(xv, k + 3), wreg[k + 3], a3);
        }
        out[(size_t)n * D + lane] = f2bf(((a0 + a1) + (a2 + a3)) * dinv[n]);
    }
}

// --- QUAD conv gather macros: each lane loads dwordx2 (8B); 16 lanes/row ->
//     one bpermute + addr + load serves 4 edges. Record for group g at index
//     P+g via bpermute byte (4g + 4P). ---------------------------------------
#define CQ_DECL(c) uint2 x##c##0, x##c##1; uint w##c##0, w##c##1;
#define CQ_GET(c, i, P, rvv) { \
    uint r = (uint)__builtin_amdgcn_ds_bpermute(vg4 + 4 * (P), (int)(rvv)); \
    w##c##i = r & 0xFFFC0000u; \
    x##c##i = *(const uint2*)((const char*)hw2p + \
                              (((r & 0x3FFFFu) << 7) + lb8)); }
#define CQ_ISSUE(c, P0, rvv) { CQ_GET(c, 0, (P0), rvv) CQ_GET(c, 1, (P0)+4, rvv) }
#define CQ_FMA1(c, i, AX, AY, AZ, AW) { \
    float wf = __uint_as_float(w##c##i); \
    AX = fmaf(wf, __uint_as_float(x##c##i.x << 16), AX); \
    AY = fmaf(wf, __uint_as_float(x##c##i.x & 0xFFFF0000u), AY); \
    AZ = fmaf(wf, __uint_as_float(x##c##i.y << 16), AZ); \
    AW = fmaf(wf, __uint_as_float(x##c##i.y & 0xFFFF0000u), AW); }
#define CQ_FMA(c, AX, AY, AZ, AW) { CQ_FMA1(c,0,AX,AY,AZ,AW) \
                                    CQ_FMA1(c,1,AX,AY,AZ,AW) }

// --- layer-1 conv, DUAL-NODE: one wave handles nodes (2m, 2m+1) as two
//     independent quad pipelines -> 12 gathers in flight, per-wave fixed
//     costs (cursor->recs->bpermute chain) amortized over 2 nodes. NU and NN
//     even -> pairs never straddle the user/item boundary. -------------------
__global__ __launch_bounds__(256) void k_conv1(
        const uint* __restrict__ hw2p, const int* __restrict__ cursor,
        const uint* __restrict__ recs, const int4* __restrict__ ovf,
        const int* __restrict__ ovfcnt, const float* __restrict__ dinv,
        const float* __restrict__ b, const float* __restrict__ g,
        const float* __restrict__ be, const float* __restrict__ U,
        const float* __restrict__ I, uint* __restrict__ out1) {
    int lane = threadIdx.x & 63;
    int m = __builtin_amdgcn_readfirstlane(blockIdx.x * 4 + (threadIdx.x >> 6));
    int n0 = m * 2;
    if (n0 >= NN) return;
    int n1 = n0 + 1;                               // NN even -> always valid
    int c0 = __builtin_amdgcn_readfirstlane(cursor[n0]); if (c0 > CAP) c0 = CAP;
    int c1 = __builtin_amdgcn_readfirstlane(cursor[n1]); if (c1 > CAP) c1 = CAP;
    uint rv0 = (lane < c0) ? recs[(size_t)n0 * CAP + lane] : 0u;
    uint rv1 = (lane < c1) ? recs[(size_t)n1 * CAP + lane] : 0u;
    const int  vg4 = (lane >> 4) << 2;             // group 0..3
    const uint lb8 = (uint)(lane & 15) << 3;       // byte offset within row
    uint2 xs0 = *(const uint2*)((const char*)hw2p + (((uint)n0 << 7) + lb8));
    uint2 xs1 = *(const uint2*)((const char*)hw2p + (((uint)n1 << 7) + lb8));
    float a0x = 0.f, a0y = 0.f, a0z = 0.f, a0w = 0.f;
    float a1x = 0.f, a1y = 0.f, a1z = 0.f, a1w = 0.f;
    int cp0 = (c0 + 7) & ~7, cp1 = (c1 + 7) & ~7;  // 0..48, wave-uniform
    CQ_DECL(A0) CQ_DECL(B0) CQ_DECL(G0)
    CQ_DECL(A1) CQ_DECL(B1) CQ_DECL(G1)
    // branch-free 12-load front: both nodes' first 24 edges
    CQ_ISSUE(A0, 0, rv0)  CQ_ISSUE(A1, 0, rv1)
    CQ_ISSUE(B0, 8, rv0)  CQ_ISSUE(B1, 8, rv1)
    CQ_ISSUE(G0, 16, rv0) CQ_ISSUE(G1, 16, rv1)
    CQ_FMA(A0, a0x, a0y, a0z, a0w)
    if (cp0 > 24) CQ_ISSUE(A0, 24, rv0)
    CQ_FMA(A1, a1x, a1y, a1z, a1w)
    if (cp1 > 24) CQ_ISSUE(A1, 24, rv1)
    CQ_FMA(B0, a0x, a0y, a0z, a0w)
    if (cp0 > 32) CQ_ISSUE(B0, 32, rv0)
    CQ_FMA(B1, a1x, a1y, a1z, a1w)
    if (cp1 > 32) CQ_ISSUE(B1, 32, rv1)
    CQ_FMA(G0, a0x, a0y, a0z, a0w)
    if (cp0 > 40) CQ_ISSUE(G0, 40, rv0)
    CQ_FMA(G1, a1x, a1y, a1z, a1w)
    if (cp1 > 40) CQ_ISSUE(G1, 40, rv1)
    if (cp0 > 24) CQ_FMA(A0, a0x, a0y, a0z, a0w)
    if (cp1 > 24) CQ_FMA(A1, a1x, a1y, a1z, a1w)
    if (cp0 > 32) CQ_FMA(B0, a0x, a0y, a0z, a0w)
    if (cp1 > 32) CQ_FMA(B1, a1x, a1y, a1z, a1w)
    if (cp0 > 40) CQ_FMA(G0, a0x, a0y, a0z, a0w)
    if (cp1 > 40) CQ_FMA(G1, a1x, a1y, a1z, a1w)
    // reduce the 4 groups (lanes q, q+16, q+32, q+48 hold partials)
    #pragma unroll
    for (int s = 32; s >= 16; s >>= 1) {
        a0x += __shfl_xor(a0x, s, 64); a0y += __shfl_xor(a0y, s, 64);
        a0z += __shfl_xor(a0z, s, 64); a0w += __shfl_xor(a0w, s, 64);
        a1x += __shfl_xor(a1x, s, 64); a1y += __shfl_xor(a1y, s, 64);
        a1z += __shfl_xor(a1z, s, 64); a1w += __shfl_xor(a1w, s, 64);
    }
    // self-loop terms
    a0x += __uint_as_float(xs0.x << 16);
    a0y += __uint_as_float(xs0.x & 0xFFFF0000u);
    a0z += __uint_as_float(xs0.y << 16);
    a0w += __uint_as_float(xs0.y & 0xFFFF0000u);
    a1x += __uint_as_float(xs1.x << 16);
    a1y += __uint_as_float(xs1.x & 0xFFFF0000u);
    a1z += __uint_as_float(xs1.y << 16);
    a1w += __uint_as_float(xs1.y & 0xFFFF0000u);
    // overflow list (normally empty); safe post-reduction (per-group replicas
    // all add the same contribution, lb8 depends on lane&15 only)
    int novf = __builtin_amdgcn_readfirstlane(ovfcnt[0]);
    if (novf > 0) {
        if (novf > OVF_MAX) novf = OVF_MAX;
        for (int j = 0; j < novf; ++j) {
            int4 e = ovf[j];
            if (e.x == n0 || e.x == n1) {
                float w = __int_as_float(e.z);
                uint2 x = *(const uint2*)((const char*)hw2p +
                                          (((uint)e.y << 7) + lb8));
                float fx = __uint_as_float(x.x << 16);
                float fy = __uint_as_float(x.x & 0xFFFF0000u);
                float fz = __uint_as_float(x.y << 16);
                float fw = __uint_as_float(x.y & 0xFFFF0000u);
                if (e.x == n0) {
                    a0x = fmaf(w, fx, a0x); a0y = fmaf(w, fy, a0y);
                    a0z = fmaf(w, fz, a0z); a0w = fmaf(w, fw, a0w);
                } else {
                    a1x = fmaf(w, fx, a1x); a1y = fmaf(w, fy, a1y);
                    a1z = fmaf(w, fz, a1z); a1w = fmaf(w, fw, a1w);
                }
            }
        }
    }
    // --- bias + LN + ReLU (quad layout) for both nodes ---
    int q = lane & 15;
    float4 bb = ((const float4*)b)[q];
    float4 gg = ((const float4*)g)[q];
    float4 ee = ((const float4*)be)[q];
    // node 0
    float di0 = dinv[n0];
    float v0 = fmaf(a0x, di0, bb.x), v1 = fmaf(a0y, di0, bb.y);
    float v2 = fmaf(a0z, di0, bb.z), v3 = fmaf(a0w, di0, bb.w);
    float s0 = (v0 + v1) + (v2 + v3);
    #pragma unroll
    for (int s = 8; s >= 1; s >>= 1) s0 += __shfl_xor(s0, s, 64);
    float m0 = s0 * (1.0f / 64.0f);
    float d00 = v0 - m0, d01 = v1 - m0, d02 = v2 - m0, d03 = v3 - m0;
    float q0 = (d00 * d00 + d01 * d01) + (d02 * d02 + d03 * d03);
    #pragma unroll
    for (int s = 8; s >= 1; s >>= 1) q0 += __shfl_xor(q0, s, 64);
    float rs0 = rsqrtf(q0 * (1.0f / 64.0f) + 1e-5f);
    float y00 = fmaxf(fmaf(d00 * rs0, gg.x, ee.x), 0.0f);
    float y01 = fmaxf(fmaf(d01 * rs0, gg.y, ee.y), 0.0f);
    float y02 = fmaxf(fmaf(d02 * rs0, gg.z, ee.z), 0.0f);
    float y03 = fmaxf(fmaf(d03 * rs0, gg.w, ee.w), 0.0f);
    // node 1
    float di1 = dinv[n1];
    float u0 = fmaf(a1x, di1, bb.x), u1 = fmaf(a1y, di1, bb.y);
    float u2 = fmaf(a1z, di1, bb.z), u3 = fmaf(a1w, di1, bb.w);
    float s1 = (u0 + u1) + (u2 + u3);
    #pragma unroll
    for (int s = 8; s >= 1; s >>= 1) s1 += __shfl_xor(s1, s, 64);
    float m1 = s1 * (1.0f / 64.0f);
    float d10 = u0 - m1, d11 = u1 - m1, d12 = u2 - m1, d13 = u3 - m1;
    float q1 = (d10 * d10 + d11 * d11) + (d12 * d12 + d13 * d13);
    #pragma unroll
    for (int s = 8; s >= 1; s >>= 1) q1 += __shfl_xor(q1, s, 64);
    float rs1 = rsqrtf(q1 * (1.0f / 64.0f) + 1e-5f);
    float y10 = fmaxf(fmaf(d10 * rs1, gg.x, ee.x), 0.0f);
    float y11 = fmaxf(fmaf(d11 * rs1, gg.y, ee.y), 0.0f);
    float y12 = fmaxf(fmaf(d12 * rs1, gg.z, ee.z), 0.0f);
    float y13 = fmaxf(fmaf(d13 * rs1, gg.w, ee.w), 0.0f);
    // --- residual + store: lanes 0-15 -> node0, 16-31 -> node1 (256B run) ---
    int which = (lane >> 4) & 1;                 // 0 for lanes 0-15, 1 for 16-31
    int nsel = n0 + which;
    const float* R = (nsel < NU) ? (U + (size_t)nsel * D)
                                 : (I + (size_t)(nsel - NU) * D);
    float4 rr = ((const float4*)R)[q];
    float z0 = which ? y10 : y00, z1 = which ? y11 : y01;
    float z2 = which ? y12 : y02, z3 = which ? y13 : y03;
    if (lane < 32) {
        uint lo = (uint)f2bf(z0 + rr.x) | ((uint)f2bf(z1 + rr.y) << 16);
        uint hi = (uint)f2bf(z2 + rr.z) | ((uint)f2bf(z3 + rr.w) << 16);
        ((uint2*)out1)[(size_t)nsel * 16 + q] = make_uint2(lo, hi);
    }
}

// --- dual-node PAIR conv accumulate for k_conv2score (unchanged) -------------
#define CB_DECL(p, c) uint p##x##c##0, p##x##c##1, p##x##c##2, p##x##c##3, \
                           p##w##c##0, p##w##c##1, p##w##c##2, p##w##c##3;
#define CB_GET(p, c, i, P, rvv) { \
    uint r = (uint)__builtin_amdgcn_ds_bpermute(vodd4 + 8 * (P), (int)(rvv)); \
    p##w##c##i = r & 0xFFFC0000u; \
    p##x##c##i = *(const uint*)((const char*)hw2p + \
                                (((r & 0x3FFFFu) << 7) + lb4)); }
#define CB_ISSUE(p, c, P0, rvv) { CB_GET(p,c,0,(P0)+0,rvv) CB_GET(p,c,1,(P0)+1,rvv) \
                                  CB_GET(p,c,2,(P0)+2,rvv) CB_GET(p,c,3,(P0)+3,rvv) }
#define CB_FMA1(p, c, i, axv, ayv) { \
    axv = fmaf(__uint_as_float(p##w##c##i), \
               __uint_as_float(p##x##c##i << 16), axv); \
    ayv = fmaf(__uint_as_float(p##w##c##i), \
               __uint_as_float(p##x##c##i & 0xFFFF0000u), ayv); }
#define CB_FMA(p, c, axv, ayv) { CB_FMA1(p,c,0,axv,ayv) CB_FMA1(p,c,1,axv,ayv) \
                                 CB_FMA1(p,c,2,axv,ayv) CB_FMA1(p,c,3,axv,ayv) }

__device__ __forceinline__ void conv_accum2_dual(int nu, int ni, int lane,
        const uint* __restrict__ hw2p, const int* __restrict__ cursor,
        const uint* __restrict__ recs, const int4* __restrict__ ovf,
        const int* __restrict__ ovfcnt, float2* outu, float2* outi) {
    int cu = __builtin_amdgcn_readfirstlane(cursor[nu]); if (cu > CAP) cu = CAP;
    int ci = __builtin_amdgcn_readfirstlane(cursor[ni]); if (ci > CAP) ci = CAP;
    uint rvu = (lane < cu) ? recs[(size_t)nu * CAP + lane] : 0u;
    uint rvi = (lane < ci) ? recs[(size_t)ni * CAP + lane] : 0u;
    const int  vodd4 = (lane >> 5) << 2;
    const uint lb4   = (uint)(lane & 31) << 2;
    uint xsu = *(const uint*)((const char*)hw2p + (((uint)nu << 7) + lb4));
    uint xsi = *(const uint*)((const char*)hw2p + (((uint)ni << 7) + lb4));
    float uax = 0.f, uay = 0.f, iax = 0.f, iay = 0.f;
    int cpu_ = (cu + 7) & ~7, cpi_ = (ci + 7) & ~7;
    CB_DECL(u, A) CB_DECL(u, B) CB_DECL(u, G)
    CB_DECL(i, A) CB_DECL(i, B) CB_DECL(i, G)
    CB_ISSUE(u, A, 0, rvu) CB_ISSUE(i, A, 0, rvi)
    CB_ISSUE(u, B, 4, rvu) CB_ISSUE(i, B, 4, rvi)
    CB_ISSUE(u, G, 8, rvu) CB_ISSUE(i, G, 8, rvi)
    CB_FMA(u, A, uax, uay) CB_FMA(i, A, iax, iay)
    if (cpu_ > 24) CB_ISSUE(u, A, 12, rvu)
    if (cpi_ > 24) CB_ISSUE(i, A, 12, rvi)
    CB_FMA(u, B, uax, uay) CB_FMA(i, B, iax, iay)
    if (cpu_ > 32) CB_ISSUE(u, B, 16, rvu)
    if (cpi_ > 32) CB_ISSUE(i, B, 16, rvi)
    CB_FMA(u, G, uax, uay) CB_FMA(i, G, iax, iay)
    if (cpu_ > 40) CB_ISSUE(u, G, 20, rvu)
    if (cpi_ > 40) CB_ISSUE(i, G, 20, rvi)
    if (cpu_ > 24) CB_FMA(u, A, uax, uay)
    if (cpi_ > 24) CB_FMA(i, A, iax, iay)
    if (cpu_ > 32) CB_FMA(u, B, uax, uay)
    if (cpi_ > 32) CB_FMA(i, B, iax, iay)
    if (cpu_ > 40) CB_FMA(u, G, uax, uay)
    if (cpi_ > 40) CB_FMA(i, G, iax, iay)
    uax += __shfl_xor(uax, 32, 64); uay += __shfl_xor(uay, 32, 64);
    iax += __shfl_xor(iax, 32, 64); iay += __shfl_xor(iay, 32, 64);
    uax += __uint_as_float(xsu << 16); uay += __uint_as_float(xsu & 0xFFFF0000u);
    iax += __uint_as_float(xsi << 16); iay += __uint_as_float(xsi & 0xFFFF0000u);
    int novf = __builtin_amdgcn_readfirstlane(ovfcnt[0]);
    if (novf > 0) {
        if (novf > OVF_MAX) novf = OVF_MAX;
        for (int j = 0; j < novf; ++j) {
            int4 e = ovf[j];
            if (e.x == nu || e.x == ni) {
                float w = __int_as_float(e.z);
                uint x = hw2p[(size_t)e.y * 32 + (lane & 31)];
                float fx = __uint_as_float(x << 16);
                float fy = __uint_as_float(x & 0xFFFF0000u);
                if (e.x == nu) { uax = fmaf(w, fx, uax); uay = fmaf(w, fy, uay); }
                else           { iax = fmaf(w, fx, iax); iay = fmaf(w, fy, iay); }
            }
        }
    }
    *outu = make_float2(uax, uay);
    *outi = make_float2(iax, iay);
}

// bias + LN + ReLU on pair layout; returns (y0,y1) for feats (2p, 2p+1)
__device__ __forceinline__ float2 ln_relu2(float2 a, float di, int p,
        const float* __restrict__ b, const float* __restrict__ g,
        const float* __restrict__ be) {
    float2 bb = ((const float2*)b)[p];
    float v0 = fmaf(a.x, di, bb.x);
    float v1 = fmaf(a.y, di, bb.y);
    float m = half_reduce_add(v0 + v1) * (1.0f / 64.0f);
    float d0 = v0 - m, d1 = v1 - m;
    float var = half_reduce_add(d0 * d0 + d1 * d1) * (1.0f / 64.0f);
    float rs = rsqrtf(var + 1e-5f);
    float2 gg = ((const float2*)g)[p];
    float2 ee = ((const float2*)be)[p];
    return make_float2(fmaxf(fmaf(d0 * rs, gg.x, ee.x), 0.0f),
                       fmaxf(fmaf(d1 * rs, gg.y, ee.y), 0.0f));
}

// ------- layer-2 GEMM: hw2b = bf16((h1 @ W1) * dinv), h1 read as bf16 --------
__global__ __launch_bounds__(256) void k_gemm2(
        const ushort* __restrict__ hb, const float* __restrict__ W,
        const float* __restrict__ dinv, ushort* __restrict__ out) {
    int lane = threadIdx.x & 63;
    float wreg[64];                         // column `lane` of W1
    #pragma unroll
    for (int k = 0; k < 64; ++k) wreg[k] = W[k * 64 + lane];
    int wpb = blockDim.x >> 6;
    int wid = blockIdx.x * wpb + (threadIdx.x >> 6);
    int tw = gridDim.x * wpb;
    for (int n = wid; n < NN; n += tw) {
        float xv = __uint_as_float((uint)hb[(size_t)n * D + lane] << 16);
        float a0 = 0.f, a1 = 0.f, a2 = 0.f, a3 = 0.f;
        #pragma unroll
        for (int k = 0; k < 64; k += 4) {
            a0 = fmaf(lane_bcast(xv, k + 0), wreg[k + 0], a0);
            a1 = fmaf(lane_bcast(xv, k + 1), wreg[k + 1], a1);
            a2 = fmaf(lane_bcast(xv, k + 2), wreg[k + 2], a2);
            a3 = fmaf(lane_bcast(xv, k + 3), wreg[k + 3], a3);
        }
        out[(size_t)n * D + lane] = f2bf(((a0 + a1) + (a2 + a3)) * dinv[n]);
    }
}

// ------- FUSED layer-2 conv (sampled) + projection + scoring ------------------
__global__ __launch_bounds__(256) void k_conv2score(
        const uint* __restrict__ hw2p, const int* __restrict__ cursor,
        const uint* __restrict__ recs, const int4* __restrict__ ovf,
        const int* __restrict__ ovfcnt, const float* __restrict__ dinv,
        const float* __restrict__ b, const float* __restrict__ g,
        const float* __restrict__ be, const int* __restrict__ users,
        const int* __restrict__ items, const uint* __restrict__ h1b,
        const float* __restrict__ Wp, const float* __restrict__ bp,
        const float* __restrict__ bu, const float* __restrict__ bi,
        const float* __restrict__ mu, float* __restrict__ out, int B) {
    __shared__ float wlds[64 * 64];        // Wp, 16 KB
    int t = threadIdx.x;
    for (int i = t; i < 64 * 64; i += 256) wlds[i] = Wp[i];
    __syncthreads();
    int lane = t & 63;
    float bpl = bp[lane];
    int q = lane & 31;
    int wpb = blockDim.x >> 6;
    int wid = blockIdx.x * wpb + (t >> 6);
    int tw = gridDim.x * wpb;
    for (int p = wid; p < B; p += tw) {
        int un = users[p];
        int in_ = NU + items[p];
        int nu = __builtin_amdgcn_readfirstlane(un);
        int ni = __builtin_amdgcn_readfirstlane(in_);
        float2 au, ai;
        conv_accum2_dual(nu, ni, lane, hw2p, cursor, recs, ovf, ovfcnt,
                         &au, &ai);
        float2 yu = ln_relu2(au, dinv[nu], q, b, g, be);
        float2 yi = ln_relu2(ai, dinv[ni], q, b, g, be);
        uint xu = h1b[(size_t)nu * 32 + q];
        uint xi = h1b[(size_t)ni * 32 + q];
        float2 hu = make_float2(yu.x + __uint_as_float(xu << 16),
                                yu.y + __uint_as_float(xu & 0xFFFF0000u));
        float2 hi = make_float2(yi.x + __uint_as_float(xi << 16),
                                yi.y + __uint_as_float(xi & 0xFFFF0000u));
        // --- projection (feat 2j from .x, 2j+1 from .y) + dot
        float pu = bpl, pi = bpl;
        #pragma unroll
        for (int j = 0; j < 32; ++j) {
            float w0 = wlds[(2 * j) * 64 + lane];
            float w1 = wlds[(2 * j + 1) * 64 + lane];
            pu = fmaf(lane_bcast(hu.x, j), w0, pu);
            pu = fmaf(lane_bcast(hu.y, j), w1, pu);
            pi = fmaf(lane_bcast(hi.x, j), w0, pi);
            pi = fmaf(lane_bcast(hi.y, j), w1, pi);
        }
        float dot = pu * pi;
        #pragma unroll
        for (int m = 32; m >= 1; m >>= 1) dot += __shfl_xor(dot, m, 64);
        if (lane == 0) {
            dot += bu[un] + bi[in_ - NU] + mu[0];
            out[p] = fminf(fmaxf(dot, 1.0f), 5.0f);
        }
    }
}

extern "C" void kernel_launch(void* const* d_in, const int* in_sizes, int n_in,
                              void* d_out, int out_size, void* d_ws, size_t ws_size,
                              hipStream_t stream) {
    const int*   users = (const int*)d_in[0];
    const int*   items = (const int*)d_in[1];
    const int*   ei2   = (const int*)d_in[2];
    const float* ew    = (const float*)d_in[3];
    const float* U     = (const float*)d_in[4];
    const float* I     = (const float*)d_in[5];
    const float* W0    = (const float*)d_in[6];
    const float* b0    = (const float*)d_in[7];
    const float* g0    = (const float*)d_in[8];
    const float* be0   = (const float*)d_in[9];
    const float* W1    = (const float*)d_in[10];
    const float* b1    = (const float*)d_in[11];
    const float* g1    = (const float*)d_in[12];
    const float* be1   = (const float*)d_in[13];
    const float* Wp    = (const float*)d_in[14];
    const float* bp    = (const float*)d_in[15];
    const float* bu    = (const float*)d_in[16];
    const float* bi    = (const float*)d_in[17];
    const float* mu    = (const float*)d_in[18];

    int B = in_sizes[0];
    int E = in_sizes[2] / 2;
    const int* srcp = ei2;
    const int* dstp = ei2 + E;

    // workspace carve-up (256B aligned)
    char* p = (char*)d_ws;
    auto alloc = [&](size_t bytes) -> char* {
        char* r = p;
        p += (bytes + 255) & ~(size_t)255;
        return r;
    };
    int*    cbuf    = (int*)  alloc((size_t)(NBINS * BCPAD + 32) * 4);  // padded bincur|spillcnt|ovfcnt
    int*    bincur  = cbuf;                       // stride BCPAD per bin
    int*    spillcnt= cbuf + NBINS * BCPAD;
    int*    ovfcnt  = cbuf + NBINS * BCPAD + 16;  // own cacheline
    int*    cursor  = (int*)  alloc((size_t)NN * 4);
    float*  dinv    = (float*)alloc((size_t)NN * 4);
    int4*   ovf     = (int4*) alloc((size_t)OVF_MAX * 16);
    uint2*  spill   = (uint2*)alloc((size_t)SPILL_CAP * 8);      // 2.1 MB
    uchar*  cnt8    = (uchar*)alloc((size_t)BIN_BLOCKS * NBINS); // 0.45 MB
    uint2*  binbuf  = (uint2*)alloc((size_t)NBINS * BINCAP * 8); // 27.4 MB
    uint*   recs    = (uint*) alloc((size_t)NN * CAP * 4);       // 28.2 MB
    ushort* hw2b    = (ushort*)alloc((size_t)NN * D * 2);        // 19.2 MB
    uint*   h1b     = (uint*) alloc((size_t)NN * 32 * 4);        // 19.2 MB (bf16)
    const uint* hw2p = (const uint*)hw2b;
    // tail ALIASES [hw2b, h1b] (38.4 MB >= 28.8 MB needed): tail is written by
    // k_bin and dead after k_regroup; hw2b is first written by k_gemm1 (after
    // regroup) and h1b by k_conv1. Lifetimes are disjoint.
    uint2*  tail    = (uint2*)hw2b;   // BIN_BLOCKS*NBINS*8 records = 28.8 MB

    hipMemsetAsync(cbuf, 0, (size_t)(NBINS * BCPAD + 32) * 4, stream);

    int gW = (NN / 2 + 3) / 4;      // one wave per NODE-PAIR, 4 waves/block

    // CSR build: bin -> regroup(+tails+spill+deg+dinv)
    k_bin<<<BIN_BLOCKS, 256, 0, stream>>>(srcp, dstp, ew, bincur, binbuf,
                                          spill, spillcnt, tail, cnt8, E);
    k_regroup<<<NBINS, 256, 0, stream>>>(bincur, binbuf, spill, spillcnt,
                                         tail, cnt8, recs, cursor, dinv,
                                         ovf, ovfcnt);

    // layer 1 (all nodes)
    k_gemm1<<<2048, 256, 0, stream>>>(U, I, W0, dinv, hw2b);
    k_conv1<<<gW, 256, 0, stream>>>(hw2p, cursor, recs, ovf, ovfcnt, dinv,
                                    b0, g0, be0, U, I, h1b);
    // layer 2: gemm all nodes (bf16 in), then fused sampled conv+proj+score
    k_gemm2<<<2048, 256, 0, stream>>>((const ushort*)h1b, W1, dinv, hw2b);
    k_conv2score<<<2048, 256, 0, stream>>>(hw2p, cursor, recs, ovf, ovfcnt, dinv,
                                           b1, g1, be1, users, items, h1b,
                                           Wp, bp, bu, bi, mu,
                                           (float*)d_out, B);
}

// Round 8
// 403.723 us; speedup vs baseline: 1.0144x; 1.0144x over previous
//
#include <hip/hip_runtime.h>

#define NU 100000
#define NI 50000
#define NN 150000   // NU + NI
#define D  64
#define CAP 47      // bucket capacity per dst; max in-degree ~44 for Poisson(21.3)
#define OVF_MAX 4096

// binning params (256-wide bins: regroup block reads exactly its own records)
#define BINSHIFT 8
#define BINW 256                 // dsts per bin
#define NBINS 586                // ceil(150000/256); 586*256 = 150016
#define BINCAP 5848              // per-bin record cap, mult of 8
#define STAGE_CAP 11             // LDS stage slots per bin (53.9KB -> 3 blocks/CU)
#define EPT 4                    // edges per thread per batch
#define SPILL_CAP 262144
#define BIN_BLOCKS 768           // 256 CUs x 3 blocks/CU, one round
#define BCPAD 16                 // bincur stride: 1 word per 64B cacheline
                                 // (R6-verified: removed k_bin's 75us atomic
                                 //  line-contention stall)

typedef unsigned int uint;
typedef unsigned short ushort;
typedef unsigned char uchar;

// ---------------- helpers ----------------
__device__ __forceinline__ float half_reduce_add(float v) {  // reduce within 32-lane half
    #pragma unroll
    for (int m = 16; m >= 1; m >>= 1) v += __shfl_xor(v, m, 64);
    return v;
}
__device__ __forceinline__ ushort f2bf(float f) {   // round-to-nearest-even
    union { float f; uint i; } c; c.f = f;
    uint r = c.i + 0x7FFF + ((c.i >> 16) & 1);
    return (ushort)(r >> 16);
}
__device__ __forceinline__ float lane_bcast(float v, int l) {
    return __int_as_float(__builtin_amdgcn_readlane(__float_as_int(v), l));
}
// bf14 weight encoding: rounded top-14 bits of f32 (w in [0,1)); decode = 1 AND
__device__ __forceinline__ uint enc14(float w) {
    uint b = __float_as_uint(w) + 0x00020000u;   // round at bit 18
    return b & 0xFFFC0000u;
}
__device__ __forceinline__ float dec14(uint r) {
    return __uint_as_float(r & 0xFFFC0000u);
}
__device__ __forceinline__ void spill_one(int d, uint s, float w,
        uint2* __restrict__ spill, int* __restrict__ spillcnt) {
    int si = atomicAdd(spillcnt, 1);
    if (si < SPILL_CAP) spill[si] = make_uint2(s | enc14(w), (uint)d);
}

// ---------------- pass 1: LDS-staged binning, line-coalesced flushes ----------
__global__ __launch_bounds__(256) void k_bin(
        const int* __restrict__ src, const int* __restrict__ dst,
        const float* __restrict__ ew, int* __restrict__ bincur,
        uint2* __restrict__ binbuf, uint2* __restrict__ spill,
        int* __restrict__ spillcnt, uint2* __restrict__ tail,
        uchar* __restrict__ cnt8, int E) {
    __shared__ uint2 stage[NBINS][STAGE_CAP];   // 51.6 KB -> 3 blocks/CU
    __shared__ int scnt[NBINS];
    int t = threadIdx.x;
    for (int i = t; i < NBINS; i += 256) scnt[i] = 0;
    __syncthreads();
    const int batch = 256 * EPT;
    for (int base = blockIdx.x * batch; base < E; base += BIN_BLOCKS * batch) {
        int dd[EPT]; uint ss[EPT]; float ww[EPT]; int ok[EPT];
        #pragma unroll
        for (int k = 0; k < EPT; ++k) {
            int e = base + k * 256 + t;
            ok[k] = (e < E);
            if (ok[k]) { dd[k] = dst[e]; ss[k] = (uint)src[e]; ww[k] = ew[e]; }
        }
        #pragma unroll
        for (int k = 0; k < EPT; ++k) {
            if (!ok[k]) continue;
            int bin = dd[k] >> BINSHIFT;
            int slot = atomicAdd(&scnt[bin], 1);
            if (slot < STAGE_CAP) {
                stage[bin][slot] = make_uint2(
                    ss[k] | ((uint)(dd[k] & (BINW - 1)) << 18),
                    (uint)__float_as_int(ww[k]));
            } else {
                spill_one(dd[k], ss[k], ww[k], spill, spillcnt);  // rare
            }
        }
        __syncthreads();
        for (int bin = t; bin < NBINS; bin += 256) {
            int c = scnt[bin]; if (c > STAGE_CAP) c = STAGE_CAP;
            while (c >= 8) {                // takes TOP 8, leaves bottom c-8
                int b0 = atomicAdd(&bincur[bin * BCPAD], 8);
                if (b0 + 8 <= BINCAP) {
                    uint4* o4 = (uint4*)(binbuf + (size_t)bin * BINCAP + b0);
                    uint2* s2 = &stage[bin][c - 8];
                    o4[0] = make_uint4(s2[0].x, s2[0].y, s2[1].x, s2[1].y);
                    o4[1] = make_uint4(s2[2].x, s2[2].y, s2[3].x, s2[3].y);
                    o4[2] = make_uint4(s2[4].x, s2[4].y, s2[5].x, s2[5].y);
                    o4[3] = make_uint4(s2[6].x, s2[6].y, s2[7].x, s2[7].y);
                } else {
                    for (int j = 0; j < 8; ++j) {
                        uint2 r = stage[bin][c - 8 + j];
                        spill_one((bin << BINSHIFT) + (int)(r.x >> 18),
                                  r.x & 0x3FFFFu, __int_as_float((int)r.y),
                                  spill, spillcnt);
                    }
                }
                c -= 8;
            }
            scnt[bin] = c;
        }
        __syncthreads();
    }
    // final residuals: c <= 7 per bin, in stage slots [0, c). Coalesced dump.
    uchar* cb = cnt8 + (size_t)blockIdx.x * NBINS;
    for (int i = t; i < NBINS; i += 256) cb[i] = (uchar)scnt[i];
    uint2* tb = tail + (size_t)blockIdx.x * (NBINS * 8);
    for (int i = t; i < NBINS * 8; i += 256) tb[i] = stage[i >> 3][i & 7];
}

// -------- pass 2: regroup + tails + spills + weighted degree + dinv -----------
__global__ __launch_bounds__(256) void k_regroup(
        const int* __restrict__ bincur, const uint2* __restrict__ binbuf,
        const uint2* __restrict__ spill, const int* __restrict__ spillcnt,
        const uint2* __restrict__ tail, const uchar* __restrict__ cnt8,
        uint* __restrict__ recs, int* __restrict__ cursor,
        float* __restrict__ dinv, int4* __restrict__ ovf,
        int* __restrict__ ovfcnt) {
    __shared__ uint image[256 * CAP];   // 47 KB, layout == recs layout
    __shared__ int cnt[256];
    __shared__ float ovfw[256];
    int t = threadIdx.x;
    int bin = blockIdx.x;
    cnt[t] = 0; ovfw[t] = 0.0f;
    __syncthreads();
    int dbase = bin << BINSHIFT;
    int nrec = bincur[bin * BCPAD]; if (nrec > BINCAP) nrec = BINCAP;
    const uint2* bb = binbuf + (size_t)bin * BINCAP;
    for (int i = t; i < nrec; i += 256) {
        uint2 r = bb[i];
        int dl = (int)(r.x >> 18);          // 8-bit dlocal, top bits zero
        int slot = atomicAdd(&cnt[dl], 1);
        uint s = r.x & 0x3FFFFu;
        float w = __int_as_float((int)r.y);
        if (slot < CAP) image[dl * CAP + slot] = enc14(w) | s;
        else {                                              // rare high-degree
            atomicAdd(&ovfw[dl], w);
            int o = atomicAdd(ovfcnt, 1);
            if (o < OVF_MAX)
                ovf[o] = make_int4(dbase + dl, (int)s, __float_as_int(w), 0);
        }
    }
    // per-block residual tails for this bin (~half of all records)
    for (int g = t; g < BIN_BLOCKS; g += 256) {
        int c = cnt8[(size_t)g * NBINS + bin];
        const uint2* tb = tail + ((size_t)g * NBINS + bin) * 8;
        for (int j = 0; j < c; ++j) {
            uint2 r = tb[j];
            int dl = (int)(r.x >> 18);
            int slot = atomicAdd(&cnt[dl], 1);
            uint s = r.x & 0x3FFFFu;
            float w = __int_as_float((int)r.y);
            if (slot < CAP) image[dl * CAP + slot] = enc14(w) | s;
            else {
                atomicAdd(&ovfw[dl], w);
                int o = atomicAdd(ovfcnt, 1);
                if (o < OVF_MAX)
                    ovf[o] = make_int4(dbase + dl, (int)s, __float_as_int(w), 0);
            }
        }
    }
    // spill entries (rare); spill words already bf14-encoded
    int ns = spillcnt[0]; if (ns > SPILL_CAP) ns = SPILL_CAP;
    for (int i = t; i < ns; i += 256) {
        uint2 e = spill[i];
        int d = (int)e.y;
        if (d < dbase || d >= dbase + BINW) continue;
        int dl = d - dbase;
        int slot = atomicAdd(&cnt[dl], 1);
        if (slot < CAP) image[dl * CAP + slot] = e.x;
        else {
            float w = dec14(e.x);
            atomicAdd(&ovfw[dl], w);
            int o = atomicAdd(ovfcnt, 1);
            if (o < OVF_MAX) ovf[o] = make_int4(d, (int)(e.x & 0x3FFFFu),
                                                __float_as_int(w), 0);
        }
    }
    __syncthreads();
    int ndl = NN - dbase; if (ndl > 256) ndl = 256;
    if (ndl <= 0) return;
    if (t < ndl) {
        int c = cnt[t];
        cursor[dbase + t] = c;
        if (c > CAP) c = CAP;
        float dg = ovfw[t];
        for (int j = 0; j < c; ++j) dg += dec14(image[t * CAP + j]);
        dinv[dbase + t] = rsqrtf(dg + 1.0f);   // self-loop weight 1 folded in
    }
    int tot = ndl * CAP;
    uint* out = recs + (size_t)dbase * CAP;
    for (int i = t; i < tot; i += 256) out[i] = image[i];  // fully coalesced
}

// ------- layer-1 GEMM: hw2b = bf16((x @ W0) * dinv), x = [U;I] f32 -----------
__global__ __launch_bounds__(256) void k_gemm1(
        const float* __restrict__ U, const float* __restrict__ I,
        const float* __restrict__ W, const float* __restrict__ dinv,
        ushort* __restrict__ out) {
    int lane = threadIdx.x & 63;
    float wreg[64];                         // column `lane` of W0
    #pragma unroll
    for (int k = 0; k < 64; ++k) wreg[k] = W[k * 64 + lane];
    int wpb = blockDim.x >> 6;
    int wid = blockIdx.x * wpb + (threadIdx.x >> 6);
    int tw = gridDim.x * wpb;
    for (int n = wid; n < NN; n += tw) {
        float xv = (n < NU) ? U[(size_t)n * D + lane]
                            : I[(size_t)(n - NU) * D + lane];
        float a0 = 0.f, a1 = 0.f, a2 = 0.f, a3 = 0.f;  // 4 chains (ILP)
        #pragma unroll
        for (int k = 0; k < 64; k += 4) {
            a0 = fmaf(lane_bcast(xv, k + 0), wreg[k + 0], a0);
            a1 = fmaf(lane_bcast(xv, k + 1), wreg[k + 1], a1);
            a2 = fmaf(lane_bcast(xv, k + 2), wreg[k + 2], a2);
            a3 = fmaf(lane_bcast(xv, k + 3), wreg[k + 3], a3);
        }
        out[(size_t)n * D + lane] = f2bf(((a0 + a1) + (a2 + a3)) * dinv[n]);
    }
}

// --- conv accumulate (R5-verified best: 74.5us): ds_bpermute record broadcast,
//     pair layout (2 feats/lane), 12-gather BRANCH-FREE front (safe: lanes >=
//     cnt carry rv=0 -> w=0, row-0 gather), guarded pipelined tail cnt > 24. --
// hw2p = (const uint*)hw2b: row n = 32 dwords, dword p = bf16 feats (2p, 2p+1).
#define CA_DECL(c) uint x##c##0, x##c##1, x##c##2, x##c##3, \
                        w##c##0, w##c##1, w##c##2, w##c##3;
#define CA_GET(c, i, P, rvv) { \
    uint r = (uint)__builtin_amdgcn_ds_bpermute(vodd4 + 8 * (P), (int)(rvv)); \
    w##c##i = r & 0xFFFC0000u; \
    x##c##i = *(const uint*)((const char*)hw2p + \
                             (((r & 0x3FFFFu) << 7) + lb4)); }
#define CA_ISSUE(c, P0, rvv) { CA_GET(c, 0, (P0)+0, rvv) CA_GET(c, 1, (P0)+1, rvv) \
                               CA_GET(c, 2, (P0)+2, rvv) CA_GET(c, 3, (P0)+3, rvv) }
#define CA_FMA1(c, i, axv, ayv) { \
    axv = fmaf(__uint_as_float(w##c##i), __uint_as_float(x##c##i << 16), axv); \
    ayv = fmaf(__uint_as_float(w##c##i), \
               __uint_as_float(x##c##i & 0xFFFF0000u), ayv); }
#define CA_FMA(c, axv, ayv) { CA_FMA1(c,0,axv,ayv) CA_FMA1(c,1,axv,ayv) \
                              CA_FMA1(c,2,axv,ayv) CA_FMA1(c,3,axv,ayv) }

__device__ __forceinline__ float2 conv_accum2(int n, int lane,
        const uint* __restrict__ hw2p, const int* __restrict__ cursor,
        const uint* __restrict__ recs, const int4* __restrict__ ovf,
        const int* __restrict__ ovfcnt) {
    int cnt = __builtin_amdgcn_readfirstlane(cursor[n]);
    if (cnt > CAP) cnt = CAP;
    uint rv = (lane < cnt) ? recs[(size_t)n * CAP + lane] : 0u;
    const int  vodd4 = (lane >> 5) << 2;          // 0 or 4: even/odd edge half
    const uint lb4   = (uint)(lane & 31) << 2;    // byte offset within row
    uint xs = *(const uint*)((const char*)hw2p + (((uint)n << 7) + lb4));
    float ax = 0.f, ay = 0.f;
    int cp = (cnt + 7) & ~7;                      // 0..48, wave-uniform
    CA_DECL(A) CA_DECL(B) CA_DECL(G)
    // branch-free 12-deep front (covers cnt <= 24, i.e. most nodes)
    CA_ISSUE(A, 0, rv) CA_ISSUE(B, 4, rv) CA_ISSUE(G, 8, rv)
    CA_FMA(A, ax, ay)
    if (cp > 24) CA_ISSUE(A, 12, rv)
    CA_FMA(B, ax, ay)
    if (cp > 32) CA_ISSUE(B, 16, rv)
    CA_FMA(G, ax, ay)
    if (cp > 40) CA_ISSUE(G, 20, rv)
    if (cp > 24) CA_FMA(A, ax, ay)
    if (cp > 32) CA_FMA(B, ax, ay)
    if (cp > 40) CA_FMA(G, ax, ay)
    // combine even/odd halves
    ax += __shfl_xor(ax, 32, 64);
    ay += __shfl_xor(ay, 32, 64);
    // self-loop term
    ax += __uint_as_float(xs << 16);
    ay += __uint_as_float(xs & 0xFFFF0000u);
    // overflow list (normally empty)
    int novf = __builtin_amdgcn_readfirstlane(ovfcnt[0]);
    if (novf > 0) {
        if (novf > OVF_MAX) novf = OVF_MAX;
        for (int j = 0; j < novf; ++j) {
            int4 e = ovf[j];
            if (e.x == n) {
                float w = __int_as_float(e.z);
                uint x = hw2p[(size_t)e.y * 32 + (lane & 31)];
                ax = fmaf(w, __int_as_float((int)(x << 16)), ax);
                ay = fmaf(w, __int_as_float((int)(x & 0xFFFF0000u)), ay);
            }
        }
    }
    return make_float2(ax, ay);
}

// bias + LN + ReLU on pair layout; returns (y0,y1) for feats (2p, 2p+1)
__device__ __forceinline__ float2 ln_relu2(float2 a, float di, int p,
        const float* __restrict__ b, const float* __restrict__ g,
        const float* __restrict__ be) {
    float2 bb = ((const float2*)b)[p];
    float v0 = fmaf(a.x, di, bb.x);
    float v1 = fmaf(a.y, di, bb.y);
    float m = half_reduce_add(v0 + v1) * (1.0f / 64.0f);
    float d0 = v0 - m, d1 = v1 - m;
    float var = half_reduce_add(d0 * d0 + d1 * d1) * (1.0f / 64.0f);
    float rs = rsqrtf(var + 1e-5f);
    float2 gg = ((const float2*)g)[p];
    float2 ee = ((const float2*)be)[p];
    return make_float2(fmaxf(fmaf(d0 * rs, gg.x, ee.x), 0.0f),
                       fmaxf(fmaf(d1 * rs, gg.y, ee.y), 0.0f));
}

// --- layer-1 conv (all nodes) + bias + LN + ReLU + residual; h1 out in bf16 --
__global__ __launch_bounds__(256) void k_conv1(
        const uint* __restrict__ hw2p, const int* __restrict__ cursor,
        const uint* __restrict__ recs, const int4* __restrict__ ovf,
        const int* __restrict__ ovfcnt, const float* __restrict__ dinv,
        const float* __restrict__ b, const float* __restrict__ g,
        const float* __restrict__ be, const float* __restrict__ U,
        const float* __restrict__ I, uint* __restrict__ out1) {
    int lane = threadIdx.x & 63;
    int n = __builtin_amdgcn_readfirstlane(blockIdx.x * 4 + (threadIdx.x >> 6));
    if (n >= NN) return;
    float2 a = conv_accum2(n, lane, hw2p, cursor, recs, ovf, ovfcnt);
    int p = lane & 31;
    float2 y = ln_relu2(a, dinv[n], p, b, g, be);
    const float* R = (n < NU) ? (U + (size_t)n * D) : (I + (size_t)(n - NU) * D);
    float2 rr = ((const float2*)R)[p];
    if (lane < 32) {
        out1[(size_t)n * 32 + p] =
            (uint)f2bf(y.x + rr.x) | ((uint)f2bf(y.y + rr.y) << 16);
    }
}

// --- dual-node PAIR conv accumulate for k_conv2score -------------------------
#define CB_DECL(p, c) uint p##x##c##0, p##x##c##1, p##x##c##2, p##x##c##3, \
                           p##w##c##0, p##w##c##1, p##w##c##2, p##w##c##3;
#define CB_GET(p, c, i, P, rvv) { \
    uint r = (uint)__builtin_amdgcn_ds_bpermute(vodd4 + 8 * (P), (int)(rvv)); \
    p##w##c##i = r & 0xFFFC0000u; \
    p##x##c##i = *(const uint*)((const char*)hw2p + \
                                (((r & 0x3FFFFu) << 7) + lb4)); }
#define CB_ISSUE(p, c, P0, rvv) { CB_GET(p,c,0,(P0)+0,rvv) CB_GET(p,c,1,(P0)+1,rvv) \
                                  CB_GET(p,c,2,(P0)+2,rvv) CB_GET(p,c,3,(P0)+3,rvv) }
#define CB_FMA1(p, c, i, axv, ayv) { \
    axv = fmaf(__uint_as_float(p##w##c##i), \
               __uint_as_float(p##x##c##i << 16), axv); \
    ayv = fmaf(__uint_as_float(p##w##c##i), \
               __uint_as_float(p##x##c##i & 0xFFFF0000u), ayv); }
#define CB_FMA(p, c, axv, ayv) { CB_FMA1(p,c,0,axv,ayv) CB_FMA1(p,c,1,axv,ayv) \
                                 CB_FMA1(p,c,2,axv,ayv) CB_FMA1(p,c,3,axv,ayv) }

__device__ __forceinline__ void conv_accum2_dual(int nu, int ni, int lane,
        const uint* __restrict__ hw2p, const int* __restrict__ cursor,
        const uint* __restrict__ recs, const int4* __restrict__ ovf,
        const int* __restrict__ ovfcnt, float2* outu, float2* outi) {
    int cu = __builtin_amdgcn_readfirstlane(cursor[nu]); if (cu > CAP) cu = CAP;
    int ci = __builtin_amdgcn_readfirstlane(cursor[ni]); if (ci > CAP) ci = CAP;
    uint rvu = (lane < cu) ? recs[(size_t)nu * CAP + lane] : 0u;
    uint rvi = (lane < ci) ? recs[(size_t)ni * CAP + lane] : 0u;
    const int  vodd4 = (lane >> 5) << 2;
    const uint lb4   = (uint)(lane & 31) << 2;
    uint xsu = *(const uint*)((const char*)hw2p + (((uint)nu << 7) + lb4));
    uint xsi = *(const uint*)((const char*)hw2p + (((uint)ni << 7) + lb4));
    float uax = 0.f, uay = 0.f, iax = 0.f, iay = 0.f;
    int cpu_ = (cu + 7) & ~7, cpi_ = (ci + 7) & ~7;
    CB_DECL(u, A) CB_DECL(u, B) CB_DECL(u, G)
    CB_DECL(i, A) CB_DECL(i, B) CB_DECL(i, G)
    CB_ISSUE(u, A, 0, rvu) CB_ISSUE(i, A, 0, rvi)
    CB_ISSUE(u, B, 4, rvu) CB_ISSUE(i, B, 4, rvi)
    CB_ISSUE(u, G, 8, rvu) CB_ISSUE(i, G, 8, rvi)
    CB_FMA(u, A, uax, uay) CB_FMA(i, A, iax, iay)
    if (cpu_ > 24) CB_ISSUE(u, A, 12, rvu)
    if (cpi_ > 24) CB_ISSUE(i, A, 12, rvi)
    CB_FMA(u, B, uax, uay) CB_FMA(i, B, iax, iay)
    if (cpu_ > 32) CB_ISSUE(u, B, 16, rvu)
    if (cpi_ > 32) CB_ISSUE(i, B, 16, rvi)
    CB_FMA(u, G, uax, uay) CB_FMA(i, G, iax, iay)
    if (cpu_ > 40) CB_ISSUE(u, G, 20, rvu)
    if (cpi_ > 40) CB_ISSUE(i, G, 20, rvi)
    if (cpu_ > 24) CB_FMA(u, A, uax, uay)
    if (cpi_ > 24) CB_FMA(i, A, iax, iay)
    if (cpu_ > 32) CB_FMA(u, B, uax, uay)
    if (cpi_ > 32) CB_FMA(i, B, iax, iay)
    if (cpu_ > 40) CB_FMA(u, G, uax, uay)
    if (cpi_ > 40) CB_FMA(i, G, iax, iay)
    uax += __shfl_xor(uax, 32, 64); uay += __shfl_xor(uay, 32, 64);
    iax += __shfl_xor(iax, 32, 64); iay += __shfl_xor(iay, 32, 64);
    uax += __uint_as_float(xsu << 16); uay += __uint_as_float(xsu & 0xFFFF0000u);
    iax += __uint_as_float(xsi << 16); iay += __uint_as_float(xsi & 0xFFFF0000u);
    int novf = __builtin_amdgcn_readfirstlane(ovfcnt[0]);
    if (novf > 0) {
        if (novf > OVF_MAX) novf = OVF_MAX;
        for (int j = 0; j < novf; ++j) {
            int4 e = ovf[j];
            if (e.x == nu || e.x == ni) {
                float w = __int_as_float(e.z);
                uint x = hw2p[(size_t)e.y * 32 + (lane & 31)];
                float fx = __uint_as_float(x << 16);
                float fy = __uint_as_float(x & 0xFFFF0000u);
                if (e.x == nu) { uax = fmaf(w, fx, uax); uay = fmaf(w, fy, uay); }
                else           { iax = fmaf(w, fx, iax); iay = fmaf(w, fy, iay); }
            }
        }
    }
    *outu = make_float2(uax, uay);
    *outi = make_float2(iax, iay);
}

// ------- layer-2 GEMM: hw2b = bf16((h1 @ W1) * dinv), h1 read as bf16 --------
__global__ __launch_bounds__(256) void k_gemm2(
        const ushort* __restrict__ hb, const float* __restrict__ W,
        const float* __restrict__ dinv, ushort* __restrict__ out) {
    int lane = threadIdx.x & 63;
    float wreg[64];                         // column `lane` of W1
    #pragma unroll
    for (int k = 0; k < 64; ++k) wreg[k] = W[k * 64 + lane];
    int wpb = blockDim.x >> 6;
    int wid = blockIdx.x * wpb + (threadIdx.x >> 6);
    int tw = gridDim.x * wpb;
    for (int n = wid; n < NN; n += tw) {
        float xv = __uint_as_float((uint)hb[(size_t)n * D + lane] << 16);
        float a0 = 0.f, a1 = 0.f, a2 = 0.f, a3 = 0.f;
        #pragma unroll
        for (int k = 0; k < 64; k += 4) {
            a0 = fmaf(lane_bcast(xv, k + 0), wreg[k + 0], a0);
            a1 = fmaf(lane_bcast(xv, k + 1), wreg[k + 1], a1);
            a2 = fmaf(lane_bcast(xv, k + 2), wreg[k + 2], a2);
            a3 = fmaf(lane_bcast(xv, k + 3), wreg[k + 3], a3);
        }
        out[(size_t)n * D + lane] = f2bf(((a0 + a1) + (a2 + a3)) * dinv[n]);
    }
}

// ------- FUSED layer-2 conv (sampled) + projection + scoring ------------------
__global__ __launch_bounds__(256) void k_conv2score(
        const uint* __restrict__ hw2p, const int* __restrict__ cursor,
        const uint* __restrict__ recs, const int4* __restrict__ ovf,
        const int* __restrict__ ovfcnt, const float* __restrict__ dinv,
        const float* __restrict__ b, const float* __restrict__ g,
        const float* __restrict__ be, const int* __restrict__ users,
        const int* __restrict__ items, const uint* __restrict__ h1b,
        const float* __restrict__ Wp, const float* __restrict__ bp,
        const float* __restrict__ bu, const float* __restrict__ bi,
        const float* __restrict__ mu, float* __restrict__ out, int B) {
    __shared__ float wlds[64 * 64];        // Wp, 16 KB
    int t = threadIdx.x;
    for (int i = t; i < 64 * 64; i += 256) wlds[i] = Wp[i];
    __syncthreads();
    int lane = t & 63;
    float bpl = bp[lane];
    int q = lane & 31;
    int wpb = blockDim.x >> 6;
    int wid = blockIdx.x * wpb + (t >> 6);
    int tw = gridDim.x * wpb;
    for (int p = wid; p < B; p += tw) {
        int un = users[p];
        int in_ = NU + items[p];
        int nu = __builtin_amdgcn_readfirstlane(un);
        int ni = __builtin_amdgcn_readfirstlane(in_);
        float2 au, ai;
        conv_accum2_dual(nu, ni, lane, hw2p, cursor, recs, ovf, ovfcnt,
                         &au, &ai);
        float2 yu = ln_relu2(au, dinv[nu], q, b, g, be);
        float2 yi = ln_relu2(ai, dinv[ni], q, b, g, be);
        uint xu = h1b[(size_t)nu * 32 + q];
        uint xi = h1b[(size_t)ni * 32 + q];
        float2 hu = make_float2(yu.x + __uint_as_float(xu << 16),
                                yu.y + __uint_as_float(xu & 0xFFFF0000u));
        float2 hi = make_float2(yi.x + __uint_as_float(xi << 16),
                                yi.y + __uint_as_float(xi & 0xFFFF0000u));
        // --- projection (feat 2j from .x, 2j+1 from .y) + dot
        float pu = bpl, pi = bpl;
        #pragma unroll
        for (int j = 0; j < 32; ++j) {
            float w0 = wlds[(2 * j) * 64 + lane];
            float w1 = wlds[(2 * j + 1) * 64 + lane];
            pu = fmaf(lane_bcast(hu.x, j), w0, pu);
            pu = fmaf(lane_bcast(hu.y, j), w1, pu);
            pi = fmaf(lane_bcast(hi.x, j), w0, pi);
            pi = fmaf(lane_bcast(hi.y, j), w1, pi);
        }
        float dot = pu * pi;
        #pragma unroll
        for (int m = 32; m >= 1; m >>= 1) dot += __shfl_xor(dot, m, 64);
        if (lane == 0) {
            dot += bu[un] + bi[in_ - NU] + mu[0];
            out[p] = fminf(fmaxf(dot, 1.0f), 5.0f);
        }
    }
}

extern "C" void kernel_launch(void* const* d_in, const int* in_sizes, int n_in,
                              void* d_out, int out_size, void* d_ws, size_t ws_size,
                              hipStream_t stream) {
    const int*   users = (const int*)d_in[0];
    const int*   items = (const int*)d_in[1];
    const int*   ei2   = (const int*)d_in[2];
    const float* ew    = (const float*)d_in[3];
    const float* U     = (const float*)d_in[4];
    const float* I     = (const float*)d_in[5];
    const float* W0    = (const float*)d_in[6];
    const float* b0    = (const float*)d_in[7];
    const float* g0    = (const float*)d_in[8];
    const float* be0   = (const float*)d_in[9];
    const float* W1    = (const float*)d_in[10];
    const float* b1    = (const float*)d_in[11];
    const float* g1    = (const float*)d_in[12];
    const float* be1   = (const float*)d_in[13];
    const float* Wp    = (const float*)d_in[14];
    const float* bp    = (const float*)d_in[15];
    const float* bu    = (const float*)d_in[16];
    const float* bi    = (const float*)d_in[17];
    const float* mu    = (const float*)d_in[18];

    int B = in_sizes[0];
    int E = in_sizes[2] / 2;
    const int* srcp = ei2;
    const int* dstp = ei2 + E;

    // workspace carve-up (256B aligned)
    char* p = (char*)d_ws;
    auto alloc = [&](size_t bytes) -> char* {
        char* r = p;
        p += (bytes + 255) & ~(size_t)255;
        return r;
    };
    int*    cbuf    = (int*)  alloc((size_t)(NBINS * BCPAD + 32) * 4);  // padded bincur|spillcnt|ovfcnt
    int*    bincur  = cbuf;                       // stride BCPAD per bin
    int*    spillcnt= cbuf + NBINS * BCPAD;
    int*    ovfcnt  = cbuf + NBINS * BCPAD + 16;  // own cacheline
    int*    cursor  = (int*)  alloc((size_t)NN * 4);
    float*  dinv    = (float*)alloc((size_t)NN * 4);
    int4*   ovf     = (int4*) alloc((size_t)OVF_MAX * 16);
    uint2*  spill   = (uint2*)alloc((size_t)SPILL_CAP * 8);      // 2.1 MB
    uchar*  cnt8    = (uchar*)alloc((size_t)BIN_BLOCKS * NBINS); // 0.45 MB
    uint2*  binbuf  = (uint2*)alloc((size_t)NBINS * BINCAP * 8); // 27.4 MB
    uint*   recs    = (uint*) alloc((size_t)NN * CAP * 4);       // 28.2 MB
    ushort* hw2b    = (ushort*)alloc((size_t)NN * D * 2);        // 19.2 MB
    uint*   h1b     = (uint*) alloc((size_t)NN * 32 * 4);        // 19.2 MB (bf16)
    const uint* hw2p = (const uint*)hw2b;
    // tail ALIASES [hw2b, h1b] (38.4 MB >= 28.8 MB needed): tail is written by
    // k_bin and dead after k_regroup; hw2b is first written by k_gemm1 (after
    // regroup) and h1b by k_conv1. Lifetimes are disjoint.
    uint2*  tail    = (uint2*)hw2b;   // BIN_BLOCKS*NBINS*8 records = 28.8 MB

    hipMemsetAsync(cbuf, 0, (size_t)(NBINS * BCPAD + 32) * 4, stream);

    int gW = (NN + 3) / 4;          // one wave per node, 4 waves/block

    // CSR build: bin -> regroup(+tails+spill+deg+dinv)
    k_bin<<<BIN_BLOCKS, 256, 0, stream>>>(srcp, dstp, ew, bincur, binbuf,
                                          spill, spillcnt, tail, cnt8, E);
    k_regroup<<<NBINS, 256, 0, stream>>>(bincur, binbuf, spill, spillcnt,
                                         tail, cnt8, recs, cursor, dinv,
                                         ovf, ovfcnt);

    // layer 1 (all nodes)
    k_gemm1<<<2048, 256, 0, stream>>>(U, I, W0, dinv, hw2b);
    k_conv1<<<gW, 256, 0, stream>>>(hw2p, cursor, recs, ovf, ovfcnt, dinv,
                                    b0, g0, be0, U, I, h1b);
    // layer 2: gemm all nodes (bf16 in), then fused sampled conv+proj+score
    k_gemm2<<<2048, 256, 0, stream>>>((const ushort*)h1b, W1, dinv, hw2b);
    k_conv2score<<<2048, 256, 0, stream>>>(hw2p, cursor, recs, ovf, ovfcnt, dinv,
                                           b1, g1, be1, users, items, h1b,
                                           Wp, bp, bu, bi, mu,
                                           (float*)d_out, B);
}

// Round 9
// 403.214 us; speedup vs baseline: 1.0157x; 1.0013x over previous
//
#include <hip/hip_runtime.h>

#define NU 100000
#define NI 50000
#define NN 150000   // NU + NI
#define D  64
#define CAP 47      // bucket capacity per dst; max in-degree ~44 for Poisson(21.3)
#define OVF_MAX 4096

// binning params (256-wide bins: regroup block reads exactly its own records)
#define BINSHIFT 8
#define BINW 256                 // dsts per bin
#define NBINS 586                // ceil(150000/256); 586*256 = 150016
#define BINCAP 5848              // per-bin record cap (mean ~3000 now, 5.8K cap)
#define STAGE_CAP 11             // LDS stage slots per bin (53.9KB -> 3 blocks/CU)
#define EPT 8                    // edges per thread per batch (R9: 4->8 halves
                                 // barrier + flush-scan rounds)
#define BIN_BLOCKS 768           // 256 CUs x 3 blocks/CU, one round
#define BCPAD 16                 // bincur stride: 1 word per 64B cacheline
                                 // (R6-verified: removed atomic line contention)
#define TAILS 5                  // residual tail slots per bin per block
                                 // (5*8B*NBINS*BIN_BLOCKS = 18.0MB <= h1b 19.2MB
                                 //  so tail can alias h1b, freeing hw2b for the
                                 //  regroup-fused gemm1; excess c>5 is direct-
                                 //  appended, ~135K scalar stores)

typedef unsigned int uint;
typedef unsigned short ushort;
typedef unsigned char uchar;

// ---------------- helpers ----------------
__device__ __forceinline__ float half_reduce_add(float v) {  // reduce within 32-lane half
    #pragma unroll
    for (int m = 16; m >= 1; m >>= 1) v += __shfl_xor(v, m, 64);
    return v;
}
__device__ __forceinline__ ushort f2bf(float f) {   // round-to-nearest-even
    union { float f; uint i; } c; c.f = f;
    uint r = c.i + 0x7FFF + ((c.i >> 16) & 1);
    return (ushort)(r >> 16);
}
__device__ __forceinline__ float lane_bcast(float v, int l) {
    return __int_as_float(__builtin_amdgcn_readlane(__float_as_int(v), l));
}
// bf14 weight encoding: rounded top-14 bits of f32 (w in [0,1)); decode = 1 AND
__device__ __forceinline__ uint enc14(float w) {
    uint b = __float_as_uint(w) + 0x00020000u;   // round at bit 18
    return b & 0xFFFC0000u;
}
__device__ __forceinline__ float dec14(uint r) {
    return __uint_as_float(r & 0xFFFC0000u);
}

// ---------------- pass 1: LDS-staged binning, line-coalesced flushes ----------
// bin record: word0 = src18 | dlocal8<<18 ; word1 = float weight bits
// Overflow (stage full / residual c>TAILS) direct-appends to binbuf (scalar
// store + cacheline-padded atomic; ~100-200K total, cheap). No spill buffer.
__global__ __launch_bounds__(256) void k_bin(
        const int* __restrict__ src, const int* __restrict__ dst,
        const float* __restrict__ ew, int* __restrict__ bincur,
        uint2* __restrict__ binbuf, uint2* __restrict__ tail,
        uchar* __restrict__ cnt8, int E) {
    __shared__ uint2 stage[NBINS][STAGE_CAP];   // 51.6 KB -> 3 blocks/CU
    __shared__ int scnt[NBINS];
    int t = threadIdx.x;
    for (int i = t; i < NBINS; i += 256) scnt[i] = 0;
    __syncthreads();
    const int batch = 256 * EPT;
    for (int base = blockIdx.x * batch; base < E; base += BIN_BLOCKS * batch) {
        int dd[EPT]; uint ss[EPT]; float ww[EPT]; int ok[EPT];
        #pragma unroll
        for (int k = 0; k < EPT; ++k) {
            int e = base + k * 256 + t;
            ok[k] = (e < E);
            if (ok[k]) { dd[k] = dst[e]; ss[k] = (uint)src[e]; ww[k] = ew[e]; }
        }
        #pragma unroll
        for (int k = 0; k < EPT; ++k) {
            if (!ok[k]) continue;
            int bin = dd[k] >> BINSHIFT;
            uint2 rec = make_uint2(
                ss[k] | ((uint)(dd[k] & (BINW - 1)) << 18),
                (uint)__float_as_int(ww[k]));
            int slot = atomicAdd(&scnt[bin], 1);
            if (slot < STAGE_CAP) {
                stage[bin][slot] = rec;
            } else {                      // stage full: direct-append (rare)
                int b0 = atomicAdd(&bincur[bin * BCPAD], 1);
                if (b0 < BINCAP) binbuf[(size_t)bin * BINCAP + b0] = rec;
            }
        }
        __syncthreads();
        for (int bin = t; bin < NBINS; bin += 256) {
            int c = scnt[bin]; if (c > STAGE_CAP) c = STAGE_CAP;
            while (c >= 8) {                // takes TOP 8, leaves bottom c-8
                int b0 = atomicAdd(&bincur[bin * BCPAD], 8);
                if (b0 + 8 <= BINCAP) {
                    uint4* o4 = (uint4*)(binbuf + (size_t)bin * BINCAP + b0);
                    uint2* s2 = &stage[bin][c - 8];
                    o4[0] = make_uint4(s2[0].x, s2[0].y, s2[1].x, s2[1].y);
                    o4[1] = make_uint4(s2[2].x, s2[2].y, s2[3].x, s2[3].y);
                    o4[2] = make_uint4(s2[4].x, s2[4].y, s2[5].x, s2[5].y);
                    o4[3] = make_uint4(s2[6].x, s2[6].y, s2[7].x, s2[7].y);
                }
                c -= 8;
            }
            scnt[bin] = c;
        }
        __syncthreads();
    }
    // final residuals: c <= 7 per bin, slots [0,c). Dump first TAILS coalesced;
    // direct-append the excess (P(c>5) small -> ~135K appends total).
    uchar* cb = cnt8 + (size_t)blockIdx.x * NBINS;
    for (int bin = t; bin < NBINS; bin += 256) {
        int c = scnt[bin]; if (c > STAGE_CAP) c = STAGE_CAP;
        if (c > TAILS) {
            for (int j = TAILS; j < c; ++j) {
                int b0 = atomicAdd(&bincur[bin * BCPAD], 1);
                if (b0 < BINCAP) binbuf[(size_t)bin * BINCAP + b0] =
                    stage[bin][j];
            }
            c = TAILS;
        }
        cb[bin] = (uchar)c;
    }
    uint2* tb = tail + (size_t)blockIdx.x * (NBINS * TAILS);
    for (int i = t; i < NBINS * TAILS; i += 256)
        tb[i] = stage[i / TAILS][i % TAILS];
}

// -- pass 2: regroup + tails + degree + dinv + FUSED layer-1 GEMM (1 blk/bin) --
// Epilogue computes hw2b = bf16((x @ W0) * dinv) for this bin's 256 nodes,
// eliminating the separate k_gemm1 dispatch; dinv is stashed in LDS (ovfw).
__global__ __launch_bounds__(256) void k_regroup(
        const int* __restrict__ bincur, const uint2* __restrict__ binbuf,
        const uint2* __restrict__ tail, const uchar* __restrict__ cnt8,
        uint* __restrict__ recs, int* __restrict__ cursor,
        float* __restrict__ dinv, int4* __restrict__ ovf,
        int* __restrict__ ovfcnt,
        const float* __restrict__ U, const float* __restrict__ I,
        const float* __restrict__ W0, ushort* __restrict__ hw2b) {
    __shared__ uint image[256 * CAP];   // 47 KB, layout == recs layout
    __shared__ int cnt[256];
    __shared__ float ovfw[256];         // overflow weights; then dinv stash
    int t = threadIdx.x;
    int bin = blockIdx.x;
    cnt[t] = 0; ovfw[t] = 0.0f;
    __syncthreads();
    int dbase = bin << BINSHIFT;
    int nrec = bincur[bin * BCPAD]; if (nrec > BINCAP) nrec = BINCAP;
    const uint2* bb = binbuf + (size_t)bin * BINCAP;
    for (int i = t; i < nrec; i += 256) {
        uint2 r = bb[i];
        int dl = (int)(r.x >> 18);          // 8-bit dlocal, top bits zero
        int slot = atomicAdd(&cnt[dl], 1);
        uint s = r.x & 0x3FFFFu;
        float w = __int_as_float((int)r.y);
        if (slot < CAP) image[dl * CAP + slot] = enc14(w) | s;
        else {                                              // rare high-degree
            atomicAdd(&ovfw[dl], w);
            int o = atomicAdd(ovfcnt, 1);
            if (o < OVF_MAX)
                ovf[o] = make_int4(dbase + dl, (int)s, __float_as_int(w), 0);
        }
    }
    // per-block residual tails for this bin (~half of all records)
    for (int g = t; g < BIN_BLOCKS; g += 256) {
        int c = cnt8[(size_t)g * NBINS + bin];
        const uint2* tb = tail + ((size_t)g * NBINS + bin) * TAILS;
        for (int j = 0; j < c; ++j) {
            uint2 r = tb[j];
            int dl = (int)(r.x >> 18);
            int slot = atomicAdd(&cnt[dl], 1);
            uint s = r.x & 0x3FFFFu;
            float w = __int_as_float((int)r.y);
            if (slot < CAP) image[dl * CAP + slot] = enc14(w) | s;
            else {
                atomicAdd(&ovfw[dl], w);
                int o = atomicAdd(ovfcnt, 1);
                if (o < OVF_MAX)
                    ovf[o] = make_int4(dbase + dl, (int)s, __float_as_int(w), 0);
            }
        }
    }
    __syncthreads();
    int ndl = NN - dbase; if (ndl > 256) ndl = 256;
    if (ndl <= 0) return;
    if (t < ndl) {
        int c = cnt[t];
        cursor[dbase + t] = c;
        if (c > CAP) c = CAP;
        float dg = ovfw[t];
        for (int j = 0; j < c; ++j) dg += dec14(image[t * CAP + j]);
        float dv = rsqrtf(dg + 1.0f);      // self-loop weight 1 folded in
        dinv[dbase + t] = dv;
        ovfw[t] = dv;                      // stash for the fused gemm below
    }
    int tot = ndl * CAP;
    uint* out = recs + (size_t)dbase * CAP;
    for (int i = t; i < tot; i += 256) out[i] = image[i];  // fully coalesced
    // ---- fused layer-1 GEMM: hw2b[n] = bf16((x[n] @ W0) * dinv[n]) ----
    __syncthreads();
    {
        int lane = t & 63;
        int wv = t >> 6;                    // wave 0..3
        float wreg[64];                     // column `lane` of W0 (L2-broadcast)
        #pragma unroll
        for (int k = 0; k < 64; ++k) wreg[k] = W0[k * 64 + lane];
        for (int j = wv; j < ndl; j += 4) {
            int n = dbase + j;
            float xv = (n < NU) ? U[(size_t)n * D + lane]
                                : I[(size_t)(n - NU) * D + lane];
            float a0 = 0.f, a1 = 0.f, a2 = 0.f, a3 = 0.f;
            #pragma unroll
            for (int k = 0; k < 64; k += 4) {
                a0 = fmaf(lane_bcast(xv, k + 0), wreg[k + 0], a0);
                a1 = fmaf(lane_bcast(xv, k + 1), wreg[k + 1], a1);
                a2 = fmaf(lane_bcast(xv, k + 2), wreg[k + 2], a2);
                a3 = fmaf(lane_bcast(xv, k + 3), wreg[k + 3], a3);
            }
            hw2b[(size_t)n * D + lane] =
                f2bf(((a0 + a1) + (a2 + a3)) * ovfw[j]);
        }
    }
}

// --- conv accumulate (R5-verified best: 74.5us): ds_bpermute record broadcast,
//     pair layout (2 feats/lane), 12-gather BRANCH-FREE front (safe: lanes >=
//     cnt carry rv=0 -> w=0, row-0 gather), guarded pipelined tail cnt > 24. --
// hw2p = (const uint*)hw2b: row n = 32 dwords, dword p = bf16 feats (2p, 2p+1).
#define CA_DECL(c) uint x##c##0, x##c##1, x##c##2, x##c##3, \
                        w##c##0, w##c##1, w##c##2, w##c##3;
#define CA_GET(c, i, P, rvv) { \
    uint r = (uint)__builtin_amdgcn_ds_bpermute(vodd4 + 8 * (P), (int)(rvv)); \
    w##c##i = r & 0xFFFC0000u; \
    x##c##i = *(const uint*)((const char*)hw2p + \
                             (((r & 0x3FFFFu) << 7) + lb4)); }
#define CA_ISSUE(c, P0, rvv) { CA_GET(c, 0, (P0)+0, rvv) CA_GET(c, 1, (P0)+1, rvv) \
                               CA_GET(c, 2, (P0)+2, rvv) CA_GET(c, 3, (P0)+3, rvv) }
#define CA_FMA1(c, i, axv, ayv) { \
    axv = fmaf(__uint_as_float(w##c##i), __uint_as_float(x##c##i << 16), axv); \
    ayv = fmaf(__uint_as_float(w##c##i), \
               __uint_as_float(x##c##i & 0xFFFF0000u), ayv); }
#define CA_FMA(c, axv, ayv) { CA_FMA1(c,0,axv,ayv) CA_FMA1(c,1,axv,ayv) \
                              CA_FMA1(c,2,axv,ayv) CA_FMA1(c,3,axv,ayv) }

__device__ __forceinline__ float2 conv_accum2(int n, int lane,
        const uint* __restrict__ hw2p, const int* __restrict__ cursor,
        const uint* __restrict__ recs, const int4* __restrict__ ovf,
        const int* __restrict__ ovfcnt) {
    int cnt = __builtin_amdgcn_readfirstlane(cursor[n]);
    if (cnt > CAP) cnt = CAP;
    uint rv = (lane < cnt) ? recs[(size_t)n * CAP + lane] : 0u;
    const int  vodd4 = (lane >> 5) << 2;          // 0 or 4: even/odd edge half
    const uint lb4   = (uint)(lane & 31) << 2;    // byte offset within row
    uint xs = *(const uint*)((const char*)hw2p + (((uint)n << 7) + lb4));
    float ax = 0.f, ay = 0.f;
    int cp = (cnt + 7) & ~7;                      // 0..48, wave-uniform
    CA_DECL(A) CA_DECL(B) CA_DECL(G)
    // branch-free 12-deep front (covers cnt <= 24, i.e. most nodes)
    CA_ISSUE(A, 0, rv) CA_ISSUE(B, 4, rv) CA_ISSUE(G, 8, rv)
    CA_FMA(A, ax, ay)
    if (cp > 24) CA_ISSUE(A, 12, rv)
    CA_FMA(B, ax, ay)
    if (cp > 32) CA_ISSUE(B, 16, rv)
    CA_FMA(G, ax, ay)
    if (cp > 40) CA_ISSUE(G, 20, rv)
    if (cp > 24) CA_FMA(A, ax, ay)
    if (cp > 32) CA_FMA(B, ax, ay)
    if (cp > 40) CA_FMA(G, ax, ay)
    // combine even/odd halves
    ax += __shfl_xor(ax, 32, 64);
    ay += __shfl_xor(ay, 32, 64);
    // self-loop term
    ax += __uint_as_float(xs << 16);
    ay += __uint_as_float(xs & 0xFFFF0000u);
    // overflow list (normally empty)
    int novf = __builtin_amdgcn_readfirstlane(ovfcnt[0]);
    if (novf > 0) {
        if (novf > OVF_MAX) novf = OVF_MAX;
        for (int j = 0; j < novf; ++j) {
            int4 e = ovf[j];
            if (e.x == n) {
                float w = __int_as_float(e.z);
                uint x = hw2p[(size_t)e.y * 32 + (lane & 31)];
                ax = fmaf(w, __int_as_float((int)(x << 16)), ax);
                ay = fmaf(w, __int_as_float((int)(x & 0xFFFF0000u)), ay);
            }
        }
    }
    return make_float2(ax, ay);
}

// bias + LN + ReLU on pair layout; returns (y0,y1) for feats (2p, 2p+1)
__device__ __forceinline__ float2 ln_relu2(float2 a, float di, int p,
        const float* __restrict__ b, const float* __restrict__ g,
        const float* __restrict__ be) {
    float2 bb = ((const float2*)b)[p];
    float v0 = fmaf(a.x, di, bb.x);
    float v1 = fmaf(a.y, di, bb.y);
    float m = half_reduce_add(v0 + v1) * (1.0f / 64.0f);
    float d0 = v0 - m, d1 = v1 - m;
    float var = half_reduce_add(d0 * d0 + d1 * d1) * (1.0f / 64.0f);
    float rs = rsqrtf(var + 1e-5f);
    float2 gg = ((const float2*)g)[p];
    float2 ee = ((const float2*)be)[p];
    return make_float2(fmaxf(fmaf(d0 * rs, gg.x, ee.x), 0.0f),
                       fmaxf(fmaf(d1 * rs, gg.y, ee.y), 0.0f));
}

// --- layer-1 conv (all nodes) + bias + LN + ReLU + residual; h1 out in bf16 --
__global__ __launch_bounds__(256) void k_conv1(
        const uint* __restrict__ hw2p, const int* __restrict__ cursor,
        const uint* __restrict__ recs, const int4* __restrict__ ovf,
        const int* __restrict__ ovfcnt, const float* __restrict__ dinv,
        const float* __restrict__ b, const float* __restrict__ g,
        const float* __restrict__ be, const float* __restrict__ U,
        const float* __restrict__ I, uint* __restrict__ out1) {
    int lane = threadIdx.x & 63;
    int n = __builtin_amdgcn_readfirstlane(blockIdx.x * 4 + (threadIdx.x >> 6));
    if (n >= NN) return;
    float2 a = conv_accum2(n, lane, hw2p, cursor, recs, ovf, ovfcnt);
    int p = lane & 31;
    float2 y = ln_relu2(a, dinv[n], p, b, g, be);
    const float* R = (n < NU) ? (U + (size_t)n * D) : (I + (size_t)(n - NU) * D);
    float2 rr = ((const float2*)R)[p];
    if (lane < 32) {
        out1[(size_t)n * 32 + p] =
            (uint)f2bf(y.x + rr.x) | ((uint)f2bf(y.y + rr.y) << 16);
    }
}

// --- dual-node PAIR conv accumulate for k_conv2score -------------------------
#define CB_DECL(p, c) uint p##x##c##0, p##x##c##1, p##x##c##2, p##x##c##3, \
                           p##w##c##0, p##w##c##1, p##w##c##2, p##w##c##3;
#define CB_GET(p, c, i, P, rvv) { \
    uint r = (uint)__builtin_amdgcn_ds_bpermute(vodd4 + 8 * (P), (int)(rvv)); \
    p##w##c##i = r & 0xFFFC0000u; \
    p##x##c##i = *(const uint*)((const char*)hw2p + \
                                (((r & 0x3FFFFu) << 7) + lb4)); }
#define CB_ISSUE(p, c, P0, rvv) { CB_GET(p,c,0,(P0)+0,rvv) CB_GET(p,c,1,(P0)+1,rvv) \
                                  CB_GET(p,c,2,(P0)+2,rvv) CB_GET(p,c,3,(P0)+3,rvv) }
#define CB_FMA1(p, c, i, axv, ayv) { \
    axv = fmaf(__uint_as_float(p##w##c##i), \
               __uint_as_float(p##x##c##i << 16), axv); \
    ayv = fmaf(__uint_as_float(p##w##c##i), \
               __uint_as_float(p##x##c##i & 0xFFFF0000u), ayv); }
#define CB_FMA(p, c, axv, ayv) { CB_FMA1(p,c,0,axv,ayv) CB_FMA1(p,c,1,axv,ayv) \
                                 CB_FMA1(p,c,2,axv,ayv) CB_FMA1(p,c,3,axv,ayv) }

__device__ __forceinline__ void conv_accum2_dual(int nu, int ni, int lane,
        const uint* __restrict__ hw2p, const int* __restrict__ cursor,
        const uint* __restrict__ recs, const int4* __restrict__ ovf,
        const int* __restrict__ ovfcnt, float2* outu, float2* outi) {
    int cu = __builtin_amdgcn_readfirstlane(cursor[nu]); if (cu > CAP) cu = CAP;
    int ci = __builtin_amdgcn_readfirstlane(cursor[ni]); if (ci > CAP) ci = CAP;
    uint rvu = (lane < cu) ? recs[(size_t)nu * CAP + lane] : 0u;
    uint rvi = (lane < ci) ? recs[(size_t)ni * CAP + lane] : 0u;
    const int  vodd4 = (lane >> 5) << 2;
    const uint lb4   = (uint)(lane & 31) << 2;
    uint xsu = *(const uint*)((const char*)hw2p + (((uint)nu << 7) + lb4));
    uint xsi = *(const uint*)((const char*)hw2p + (((uint)ni << 7) + lb4));
    float uax = 0.f, uay = 0.f, iax = 0.f, iay = 0.f;
    int cpu_ = (cu + 7) & ~7, cpi_ = (ci + 7) & ~7;
    CB_DECL(u, A) CB_DECL(u, B) CB_DECL(u, G)
    CB_DECL(i, A) CB_DECL(i, B) CB_DECL(i, G)
    CB_ISSUE(u, A, 0, rvu) CB_ISSUE(i, A, 0, rvi)
    CB_ISSUE(u, B, 4, rvu) CB_ISSUE(i, B, 4, rvi)
    CB_ISSUE(u, G, 8, rvu) CB_ISSUE(i, G, 8, rvi)
    CB_FMA(u, A, uax, uay) CB_FMA(i, A, iax, iay)
    if (cpu_ > 24) CB_ISSUE(u, A, 12, rvu)
    if (cpi_ > 24) CB_ISSUE(i, A, 12, rvi)
    CB_FMA(u, B, uax, uay) CB_FMA(i, B, iax, iay)
    if (cpu_ > 32) CB_ISSUE(u, B, 16, rvu)
    if (cpi_ > 32) CB_ISSUE(i, B, 16, rvi)
    CB_FMA(u, G, uax, uay) CB_FMA(i, G, iax, iay)
    if (cpu_ > 40) CB_ISSUE(u, G, 20, rvu)
    if (cpi_ > 40) CB_ISSUE(i, G, 20, rvi)
    if (cpu_ > 24) CB_FMA(u, A, uax, uay)
    if (cpi_ > 24) CB_FMA(i, A, iax, iay)
    if (cpu_ > 32) CB_FMA(u, B, uax, uay)
    if (cpi_ > 32) CB_FMA(i, B, iax, iay)
    if (cpu_ > 40) CB_FMA(u, G, uax, uay)
    if (cpi_ > 40) CB_FMA(i, G, iax, iay)
    uax += __shfl_xor(uax, 32, 64); uay += __shfl_xor(uay, 32, 64);
    iax += __shfl_xor(iax, 32, 64); iay += __shfl_xor(iay, 32, 64);
    uax += __uint_as_float(xsu << 16); uay += __uint_as_float(xsu & 0xFFFF0000u);
    iax += __uint_as_float(xsi << 16); iay += __uint_as_float(xsi & 0xFFFF0000u);
    int novf = __builtin_amdgcn_readfirstlane(ovfcnt[0]);
    if (novf > 0) {
        if (novf > OVF_MAX) novf = OVF_MAX;
        for (int j = 0; j < novf; ++j) {
            int4 e = ovf[j];
            if (e.x == nu || e.x == ni) {
                float w = __int_as_float(e.z);
                uint x = hw2p[(size_t)e.y * 32 + (lane & 31)];
                float fx = __uint_as_float(x << 16);
                float fy = __uint_as_float(x & 0xFFFF0000u);
                if (e.x == nu) { uax = fmaf(w, fx, uax); uay = fmaf(w, fy, uay); }
                else           { iax = fmaf(w, fx, iax); iay = fmaf(w, fy, iay); }
            }
        }
    }
    *outu = make_float2(uax, uay);
    *outi = make_float2(iax, iay);
}

// ------- layer-2 GEMM: hw2b = bf16((h1 @ W1) * dinv), h1 read as bf16 --------
__global__ __launch_bounds__(256) void k_gemm2(
        const ushort* __restrict__ hb, const float* __restrict__ W,
        const float* __restrict__ dinv, ushort* __restrict__ out) {
    int lane = threadIdx.x & 63;
    float wreg[64];                         // column `lane` of W1
    #pragma unroll
    for (int k = 0; k < 64; ++k) wreg[k] = W[k * 64 + lane];
    int wpb = blockDim.x >> 6;
    int wid = blockIdx.x * wpb + (threadIdx.x >> 6);
    int tw = gridDim.x * wpb;
    for (int n = wid; n < NN; n += tw) {
        float xv = __uint_as_float((uint)hb[(size_t)n * D + lane] << 16);
        float a0 = 0.f, a1 = 0.f, a2 = 0.f, a3 = 0.f;
        #pragma unroll
        for (int k = 0; k < 64; k += 4) {
            a0 = fmaf(lane_bcast(xv, k + 0), wreg[k + 0], a0);
            a1 = fmaf(lane_bcast(xv, k + 1), wreg[k + 1], a1);
            a2 = fmaf(lane_bcast(xv, k + 2), wreg[k + 2], a2);
            a3 = fmaf(lane_bcast(xv, k + 3), wreg[k + 3], a3);
        }
        out[(size_t)n * D + lane] = f2bf(((a0 + a1) + (a2 + a3)) * dinv[n]);
    }
}

// ------- FUSED layer-2 conv (sampled) + projection + scoring ------------------
__global__ __launch_bounds__(256) void k_conv2score(
        const uint* __restrict__ hw2p, const int* __restrict__ cursor,
        const uint* __restrict__ recs, const int4* __restrict__ ovf,
        const int* __restrict__ ovfcnt, const float* __restrict__ dinv,
        const float* __restrict__ b, const float* __restrict__ g,
        const float* __restrict__ be, const int* __restrict__ users,
        const int* __restrict__ items, const uint* __restrict__ h1b,
        const float* __restrict__ Wp, const float* __restrict__ bp,
        const float* __restrict__ bu, const float* __restrict__ bi,
        const float* __restrict__ mu, float* __restrict__ out, int B) {
    __shared__ float wlds[64 * 64];        // Wp, 16 KB
    int t = threadIdx.x;
    for (int i = t; i < 64 * 64; i += 256) wlds[i] = Wp[i];
    __syncthreads();
    int lane = t & 63;
    float bpl = bp[lane];
    int q = lane & 31;
    int wpb = blockDim.x >> 6;
    int wid = blockIdx.x * wpb + (t >> 6);
    int tw = gridDim.x * wpb;
    for (int p = wid; p < B; p += tw) {
        int un = users[p];
        int in_ = NU + items[p];
        int nu = __builtin_amdgcn_readfirstlane(un);
        int ni = __builtin_amdgcn_readfirstlane(in_);
        float2 au, ai;
        conv_accum2_dual(nu, ni, lane, hw2p, cursor, recs, ovf, ovfcnt,
                         &au, &ai);
        float2 yu = ln_relu2(au, dinv[nu], q, b, g, be);
        float2 yi = ln_relu2(ai, dinv[ni], q, b, g, be);
        uint xu = h1b[(size_t)nu * 32 + q];
        uint xi = h1b[(size_t)ni * 32 + q];
        float2 hu = make_float2(yu.x + __uint_as_float(xu << 16),
                                yu.y + __uint_as_float(xu & 0xFFFF0000u));
        float2 hi = make_float2(yi.x + __uint_as_float(xi << 16),
                                yi.y + __uint_as_float(xi & 0xFFFF0000u));
        // --- projection (feat 2j from .x, 2j+1 from .y) + dot
        float pu = bpl, pi = bpl;
        #pragma unroll
        for (int j = 0; j < 32; ++j) {
            float w0 = wlds[(2 * j) * 64 + lane];
            float w1 = wlds[(2 * j + 1) * 64 + lane];
            pu = fmaf(lane_bcast(hu.x, j), w0, pu);
            pu = fmaf(lane_bcast(hu.y, j), w1, pu);
            pi = fmaf(lane_bcast(hi.x, j), w0, pi);
            pi = fmaf(lane_bcast(hi.y, j), w1, pi);
        }
        float dot = pu * pi;
        #pragma unroll
        for (int m = 32; m >= 1; m >>= 1) dot += __shfl_xor(dot, m, 64);
        if (lane == 0) {
            dot += bu[un] + bi[in_ - NU] + mu[0];
            out[p] = fminf(fmaxf(dot, 1.0f), 5.0f);
        }
    }
}

extern "C" void kernel_launch(void* const* d_in, const int* in_sizes, int n_in,
                              void* d_out, int out_size, void* d_ws, size_t ws_size,
                              hipStream_t stream) {
    const int*   users = (const int*)d_in[0];
    const int*   items = (const int*)d_in[1];
    const int*   ei2   = (const int*)d_in[2];
    const float* ew    = (const float*)d_in[3];
    const float* U     = (const float*)d_in[4];
    const float* I     = (const float*)d_in[5];
    const float* W0    = (const float*)d_in[6];
    const float* b0    = (const float*)d_in[7];
    const float* g0    = (const float*)d_in[8];
    const float* be0   = (const float*)d_in[9];
    const float* W1    = (const float*)d_in[10];
    const float* b1    = (const float*)d_in[11];
    const float* g1    = (const float*)d_in[12];
    const float* be1   = (const float*)d_in[13];
    const float* Wp    = (const float*)d_in[14];
    const float* bp    = (const float*)d_in[15];
    const float* bu    = (const float*)d_in[16];
    const float* bi    = (const float*)d_in[17];
    const float* mu    = (const float*)d_in[18];

    int B = in_sizes[0];
    int E = in_sizes[2] / 2;
    const int* srcp = ei2;
    const int* dstp = ei2 + E;

    // workspace carve-up (256B aligned)
    char* p = (char*)d_ws;
    auto alloc = [&](size_t bytes) -> char* {
        char* r = p;
        p += (bytes + 255) & ~(size_t)255;
        return r;
    };
    int*    cbuf    = (int*)  alloc((size_t)(NBINS * BCPAD + 32) * 4);  // padded bincur|ovfcnt
    int*    bincur  = cbuf;                       // stride BCPAD per bin
    int*    ovfcnt  = cbuf + NBINS * BCPAD + 16;  // own cacheline
    int*    cursor  = (int*)  alloc((size_t)NN * 4);
    float*  dinv    = (float*)alloc((size_t)NN * 4);
    int4*   ovf     = (int4*) alloc((size_t)OVF_MAX * 16);
    uchar*  cnt8    = (uchar*)alloc((size_t)BIN_BLOCKS * NBINS); // 0.45 MB
    uint2*  binbuf  = (uint2*)alloc((size_t)NBINS * BINCAP * 8); // 27.4 MB
    uint*   recs    = (uint*) alloc((size_t)NN * CAP * 4);       // 28.2 MB
    ushort* hw2b    = (ushort*)alloc((size_t)NN * D * 2);        // 19.2 MB
    uint*   h1b     = (uint*) alloc((size_t)NN * 32 * 4);        // 19.2 MB (bf16)
    const uint* hw2p = (const uint*)hw2b;
    // tail ALIASES h1b ONLY (18.0 MB <= 19.2 MB): tail is written by k_bin and
    // dead after k_regroup; h1b is first written by k_conv1 (after regroup).
    // hw2b must stay un-aliased because k_regroup's fused gemm writes it while
    // other blocks still read their tails.
    uint2*  tail    = (uint2*)h1b;   // BIN_BLOCKS*NBINS*TAILS records = 18.0 MB

    hipMemsetAsync(cbuf, 0, (size_t)(NBINS * BCPAD + 32) * 4, stream);

    int gW = (NN + 3) / 4;          // one wave per node, 4 waves/block

    // CSR build: bin -> regroup(+tails+deg+dinv+FUSED gemm1)
    k_bin<<<BIN_BLOCKS, 256, 0, stream>>>(srcp, dstp, ew, bincur, binbuf,
                                          tail, cnt8, E);
    k_regroup<<<NBINS, 256, 0, stream>>>(bincur, binbuf, tail, cnt8,
                                         recs, cursor, dinv, ovf, ovfcnt,
                                         U, I, W0, hw2b);

    // layer 1 conv (all nodes) -> h1 (bf16)
    k_conv1<<<gW, 256, 0, stream>>>(hw2p, cursor, recs, ovf, ovfcnt, dinv,
                                    b0, g0, be0, U, I, h1b);
    // layer 2: gemm all nodes (bf16 in), then fused sampled conv+proj+score
    k_gemm2<<<2048, 256, 0, stream>>>((const ushort*)h1b, W1, dinv, hw2b);
    k_conv2score<<<2048, 256, 0, stream>>>(hw2p, cursor, recs, ovf, ovfcnt, dinv,
                                           b1, g1, be1, users, items, h1b,
                                           Wp, bp, bu, bi, mu,
                                           (float*)d_out, B);
}

// Round 11
// 400.223 us; speedup vs baseline: 1.0233x; 1.0075x over previous
//
#include <hip/hip_runtime.h>

#define NU 100000
#define NI 50000
#define NN 150000   // NU + NI
#define D  64
#define CAP 47      // bucket capacity per dst; max in-degree ~44 for Poisson(21.3)
#define OVF_MAX 4096

// binning params (256-wide bins: regroup block reads exactly its own records)
#define BINSHIFT 8
#define BINW 256                 // dsts per bin
#define NBINS 586                // ceil(150000/256); 586*256 = 150016
#define BINCAP 5848              // per-bin record cap
#define STAGE_CAP 11             // LDS stage slots per bin (53.9KB -> 3 blocks/CU)
#define EPT 8                    // edges per thread per batch
#define BIN_BLOCKS 768           // 256 CUs x 3 blocks/CU, one round
#define BCPAD 16                 // bincur stride: 1 word per 64B cacheline
                                 // (R6-verified: removed atomic line contention)
#define TAILS 5                  // residual tail slots per bin per block
// R10: tail layout TRANSPOSED to [bin][g][slot] and per-(bin,g) count embedded
// in slot0 bits [28:26] (records use bits 0..25 only). k_regroup's tail read
// becomes a contiguous 30KB stream per bin (was 768 reads at 23.4KB stride,
// the cause of R9's 86us @ 15% HBM / 20% occupancy). cnt8 buffer eliminated.

typedef unsigned int uint;
typedef unsigned short ushort;
typedef unsigned char uchar;

// ---------------- helpers ----------------
__device__ __forceinline__ float half_reduce_add(float v) {  // reduce within 32-lane half
    #pragma unroll
    for (int m = 16; m >= 1; m >>= 1) v += __shfl_xor(v, m, 64);
    return v;
}
__device__ __forceinline__ ushort f2bf(float f) {   // round-to-nearest-even
    union { float f; uint i; } c; c.f = f;
    uint r = c.i + 0x7FFF + ((c.i >> 16) & 1);
    return (ushort)(r >> 16);
}
__device__ __forceinline__ float lane_bcast(float v, int l) {
    return __int_as_float(__builtin_amdgcn_readlane(__float_as_int(v), l));
}
// bf14 weight encoding: rounded top-14 bits of f32 (w in [0,1)); decode = 1 AND
__device__ __forceinline__ uint enc14(float w) {
    uint b = __float_as_uint(w) + 0x00020000u;   // round at bit 18
    return b & 0xFFFC0000u;
}
__device__ __forceinline__ float dec14(uint r) {
    return __uint_as_float(r & 0xFFFC0000u);
}

// ---------------- pass 1: LDS-staged binning, line-coalesced flushes ----------
// bin record: word0 = src18 | dlocal8<<18 (bits 26-31 free) ; word1 = f32 w
// Overflow (stage full / residual c>TAILS) direct-appends to binbuf (scalar
// store + cacheline-padded atomic; rare). No spill buffer.
__global__ __launch_bounds__(256) void k_bin(
        const int* __restrict__ src, const int* __restrict__ dst,
        const float* __restrict__ ew, int* __restrict__ bincur,
        uint2* __restrict__ binbuf, uint2* __restrict__ tail, int E) {
    __shared__ uint2 stage[NBINS][STAGE_CAP];   // 51.6 KB -> 3 blocks/CU
    __shared__ int scnt[NBINS];
    int t = threadIdx.x;
    for (int i = t; i < NBINS; i += 256) scnt[i] = 0;
    __syncthreads();
    const int batch = 256 * EPT;
    for (int base = blockIdx.x * batch; base < E; base += BIN_BLOCKS * batch) {
        int dd[EPT]; uint ss[EPT]; float ww[EPT]; int ok[EPT];
        #pragma unroll
        for (int k = 0; k < EPT; ++k) {
            int e = base + k * 256 + t;
            ok[k] = (e < E);
            if (ok[k]) { dd[k] = dst[e]; ss[k] = (uint)src[e]; ww[k] = ew[e]; }
        }
        #pragma unroll
        for (int k = 0; k < EPT; ++k) {
            if (!ok[k]) continue;
            int bin = dd[k] >> BINSHIFT;
            uint2 rec = make_uint2(
                ss[k] | ((uint)(dd[k] & (BINW - 1)) << 18),
                (uint)__float_as_int(ww[k]));
            int slot = atomicAdd(&scnt[bin], 1);
            if (slot < STAGE_CAP) {
                stage[bin][slot] = rec;
            } else {                      // stage full: direct-append (rare)
                int b0 = atomicAdd(&bincur[bin * BCPAD], 1);
                if (b0 < BINCAP) binbuf[(size_t)bin * BINCAP + b0] = rec;
            }
        }
        __syncthreads();
        for (int bin = t; bin < NBINS; bin += 256) {
            int c = scnt[bin]; if (c > STAGE_CAP) c = STAGE_CAP;
            while (c >= 8) {                // takes TOP 8, leaves bottom c-8
                int b0 = atomicAdd(&bincur[bin * BCPAD], 8);
                if (b0 + 8 <= BINCAP) {
                    uint4* o4 = (uint4*)(binbuf + (size_t)bin * BINCAP + b0);
                    uint2* s2 = &stage[bin][c - 8];
                    o4[0] = make_uint4(s2[0].x, s2[0].y, s2[1].x, s2[1].y);
                    o4[1] = make_uint4(s2[2].x, s2[2].y, s2[3].x, s2[3].y);
                    o4[2] = make_uint4(s2[4].x, s2[4].y, s2[5].x, s2[5].y);
                    o4[3] = make_uint4(s2[6].x, s2[6].y, s2[7].x, s2[7].y);
                }
                c -= 8;
            }
            scnt[bin] = c;
        }
        __syncthreads();
    }
    // residuals: clamp to TAILS (direct-append the excess), store clamped count
    for (int bin = t; bin < NBINS; bin += 256) {
        int c = scnt[bin]; if (c > STAGE_CAP) c = STAGE_CAP;
        if (c > TAILS) {
            for (int j = TAILS; j < c; ++j) {
                int b0 = atomicAdd(&bincur[bin * BCPAD], 1);
                if (b0 < BINCAP) binbuf[(size_t)bin * BINCAP + b0] =
                    stage[bin][j];
            }
            c = TAILS;
        }
        scnt[bin] = c;
    }
    __syncthreads();
    // transposed dump: tail[bin][g=blockIdx][slot], count in slot0 bits 26+
    for (int i = t; i < NBINS * TAILS; i += 256) {
        int bin = i / TAILS, slot = i % TAILS;
        uint2 r = stage[bin][slot];
        if (slot == 0) r.x = (r.x & 0x03FFFFFFu) | ((uint)scnt[bin] << 26);
        tail[((size_t)bin * BIN_BLOCKS + blockIdx.x) * TAILS + slot] = r;
    }
}

// -- pass 2: regroup + tails + degree + dinv + FUSED layer-1 GEMM (1 blk/bin) --
// 512 threads (R10): grid is fixed at 586 blocks (2.3/CU), so 8 waves/block
// doubles resident waves; LDS 49KB still allows 3 blocks/CU.
__global__ __launch_bounds__(512) void k_regroup(
        const int* __restrict__ bincur, const uint2* __restrict__ binbuf,
        const uint2* __restrict__ tail,
        uint* __restrict__ recs, int* __restrict__ cursor,
        float* __restrict__ dinv, int4* __restrict__ ovf,
        int* __restrict__ ovfcnt,
        const float* __restrict__ U, const float* __restrict__ I,
        const float* __restrict__ W0, ushort* __restrict__ hw2b) {
    __shared__ uint image[256 * CAP];   // 47 KB, layout == recs layout
    __shared__ int cnt[256];
    __shared__ float ovfw[256];         // overflow weights; then dinv stash
    int t = threadIdx.x;
    int bin = blockIdx.x;
    if (t < 256) { cnt[t] = 0; ovfw[t] = 0.0f; }
    __syncthreads();
    int dbase = bin << BINSHIFT;
    int nrec = bincur[bin * BCPAD]; if (nrec > BINCAP) nrec = BINCAP;
    const uint2* bb = binbuf + (size_t)bin * BINCAP;
    for (int i = t; i < nrec; i += 512) {
        uint2 r = bb[i];
        int dl = (int)(r.x >> 18);          // binbuf recs have clean top bits
        int slot = atomicAdd(&cnt[dl], 1);
        uint s = r.x & 0x3FFFFu;
        float w = __int_as_float((int)r.y);
        if (slot < CAP) image[dl * CAP + slot] = enc14(w) | s;
        else {                                              // rare high-degree
            atomicAdd(&ovfw[dl], w);
            int o = atomicAdd(ovfcnt, 1);
            if (o < OVF_MAX)
                ovf[o] = make_int4(dbase + dl, (int)s, __float_as_int(w), 0);
        }
    }
    // per-block residual tails: CONTIGUOUS stream for this bin (transposed
    // layout), count embedded in slot0 bits [28:26]
    const uint2* tbin = tail + (size_t)bin * BIN_BLOCKS * TAILS;
    for (int g = t; g < BIN_BLOCKS; g += 512) {
        const uint2* tb = tbin + (size_t)g * TAILS;
        uint2 r0 = tb[0];
        int c = (int)(r0.x >> 26);          // 0..TAILS
        r0.x &= 0x03FFFFFFu;
        for (int j = 0; j < c; ++j) {
            uint2 r = (j == 0) ? r0 : tb[j];
            int dl = (int)((r.x >> 18) & 0xFFu);
            int slot = atomicAdd(&cnt[dl], 1);
            uint s = r.x & 0x3FFFFu;
            float w = __int_as_float((int)r.y);
            if (slot < CAP) image[dl * CAP + slot] = enc14(w) | s;
            else {
                atomicAdd(&ovfw[dl], w);
                int o = atomicAdd(ovfcnt, 1);
                if (o < OVF_MAX)
                    ovf[o] = make_int4(dbase + dl, (int)s, __float_as_int(w), 0);
            }
        }
    }
    __syncthreads();
    int ndl = NN - dbase; if (ndl > 256) ndl = 256;
    if (ndl <= 0) return;
    if (t < ndl) {
        int c = cnt[t];
        cursor[dbase + t] = c;
        if (c > CAP) c = CAP;
        float dg = ovfw[t];
        for (int j = 0; j < c; ++j) dg += dec14(image[t * CAP + j]);
        float dv = rsqrtf(dg + 1.0f);      // self-loop weight 1 folded in
        dinv[dbase + t] = dv;
        ovfw[t] = dv;                      // stash for the fused gemm below
    }
    int tot = ndl * CAP;
    uint* out = recs + (size_t)dbase * CAP;
    for (int i = t; i < tot; i += 512) out[i] = image[i];  // fully coalesced
    // ---- fused layer-1 GEMM: hw2b[n] = bf16((x[n] @ W0) * dinv[n]) ----
    __syncthreads();
    {
        int lane = t & 63;
        int wv = t >> 6;                    // wave 0..7
        float wreg[64];                     // column `lane` of W0 (L2-broadcast)
        #pragma unroll
        for (int k = 0; k < 64; ++k) wreg[k] = W0[k * 64 + lane];
        for (int j = wv; j < ndl; j += 8) {
            int n = dbase + j;
            float xv = (n < NU) ? U[(size_t)n * D + lane]
                                : I[(size_t)(n - NU) * D + lane];
            float a0 = 0.f, a1 = 0.f, a2 = 0.f, a3 = 0.f;
            #pragma unroll
            for (int k = 0; k < 64; k += 4) {
                a0 = fmaf(lane_bcast(xv, k + 0), wreg[k + 0], a0);
                a1 = fmaf(lane_bcast(xv, k + 1), wreg[k + 1], a1);
                a2 = fmaf(lane_bcast(xv, k + 2), wreg[k + 2], a2);
                a3 = fmaf(lane_bcast(xv, k + 3), wreg[k + 3], a3);
            }
            hw2b[(size_t)n * D + lane] =
                f2bf(((a0 + a1) + (a2 + a3)) * ovfw[j]);
        }
    }
}

// --- conv accumulate (R5-verified best: 74.5us): ds_bpermute record broadcast,
//     pair layout (2 feats/lane), 12-gather BRANCH-FREE front (safe: lanes >=
//     cnt carry rv=0 -> w=0, row-0 gather), guarded pipelined tail cnt > 24. --
// hw2p = (const uint*)hw2b: row n = 32 dwords, dword p = bf16 feats (2p, 2p+1).
#define CA_DECL(c) uint x##c##0, x##c##1, x##c##2, x##c##3, \
                        w##c##0, w##c##1, w##c##2, w##c##3;
#define CA_GET(c, i, P, rvv) { \
    uint r = (uint)__builtin_amdgcn_ds_bpermute(vodd4 + 8 * (P), (int)(rvv)); \
    w##c##i = r & 0xFFFC0000u; \
    x##c##i = *(const uint*)((const char*)hw2p + \
                             (((r & 0x3FFFFu) << 7) + lb4)); }
#define CA_ISSUE(c, P0, rvv) { CA_GET(c, 0, (P0)+0, rvv) CA_GET(c, 1, (P0)+1, rvv) \
                               CA_GET(c, 2, (P0)+2, rvv) CA_GET(c, 3, (P0)+3, rvv) }
#define CA_FMA1(c, i, axv, ayv) { \
    axv = fmaf(__uint_as_float(w##c##i), __uint_as_float(x##c##i << 16), axv); \
    ayv = fmaf(__uint_as_float(w##c##i), \
               __uint_as_float(x##c##i & 0xFFFF0000u), ayv); }
#define CA_FMA(c, axv, ayv) { CA_FMA1(c,0,axv,ayv) CA_FMA1(c,1,axv,ayv) \
                              CA_FMA1(c,2,axv,ayv) CA_FMA1(c,3,axv,ayv) }

__device__ __forceinline__ float2 conv_accum2(int n, int lane,
        const uint* __restrict__ hw2p, const int* __restrict__ cursor,
        const uint* __restrict__ recs, const int4* __restrict__ ovf,
        const int* __restrict__ ovfcnt) {
    int cnt = __builtin_amdgcn_readfirstlane(cursor[n]);
    if (cnt > CAP) cnt = CAP;
    uint rv = (lane < cnt) ? recs[(size_t)n * CAP + lane] : 0u;
    const int  vodd4 = (lane >> 5) << 2;          // 0 or 4: even/odd edge half
    const uint lb4   = (uint)(lane & 31) << 2;    // byte offset within row
    uint xs = *(const uint*)((const char*)hw2p + (((uint)n << 7) + lb4));
    float ax = 0.f, ay = 0.f;
    int cp = (cnt + 7) & ~7;                      // 0..48, wave-uniform
    CA_DECL(A) CA_DECL(B) CA_DECL(G)
    // branch-free 12-deep front (covers cnt <= 24, i.e. most nodes)
    CA_ISSUE(A, 0, rv) CA_ISSUE(B, 4, rv) CA_ISSUE(G, 8, rv)
    CA_FMA(A, ax, ay)
    if (cp > 24) CA_ISSUE(A, 12, rv)
    CA_FMA(B, ax, ay)
    if (cp > 32) CA_ISSUE(B, 16, rv)
    CA_FMA(G, ax, ay)
    if (cp > 40) CA_ISSUE(G, 20, rv)
    if (cp > 24) CA_FMA(A, ax, ay)
    if (cp > 32) CA_FMA(B, ax, ay)
    if (cp > 40) CA_FMA(G, ax, ay)
    // combine even/odd halves
    ax += __shfl_xor(ax, 32, 64);
    ay += __shfl_xor(ay, 32, 64);
    // self-loop term
    ax += __uint_as_float(xs << 16);
    ay += __uint_as_float(xs & 0xFFFF0000u);
    // overflow list (normally empty)
    int novf = __builtin_amdgcn_readfirstlane(ovfcnt[0]);
    if (novf > 0) {
        if (novf > OVF_MAX) novf = OVF_MAX;
        for (int j = 0; j < novf; ++j) {
            int4 e = ovf[j];
            if (e.x == n) {
                float w = __int_as_float(e.z);
                uint x = hw2p[(size_t)e.y * 32 + (lane & 31)];
                ax = fmaf(w, __int_as_float((int)(x << 16)), ax);
                ay = fmaf(w, __int_as_float((int)(x & 0xFFFF0000u)), ay);
            }
        }
    }
    return make_float2(ax, ay);
}

// bias + LN + ReLU on pair layout; returns (y0,y1) for feats (2p, 2p+1)
__device__ __forceinline__ float2 ln_relu2(float2 a, float di, int p,
        const float* __restrict__ b, const float* __restrict__ g,
        const float* __restrict__ be) {
    float2 bb = ((const float2*)b)[p];
    float v0 = fmaf(a.x, di, bb.x);
    float v1 = fmaf(a.y, di, bb.y);
    float m = half_reduce_add(v0 + v1) * (1.0f / 64.0f);
    float d0 = v0 - m, d1 = v1 - m;
    float var = half_reduce_add(d0 * d0 + d1 * d1) * (1.0f / 64.0f);
    float rs = rsqrtf(var + 1e-5f);
    float2 gg = ((const float2*)g)[p];
    float2 ee = ((const float2*)be)[p];
    return make_float2(fmaxf(fmaf(d0 * rs, gg.x, ee.x), 0.0f),
                       fmaxf(fmaf(d1 * rs, gg.y, ee.y), 0.0f));
}

// --- layer-1 conv (all nodes) + bias + LN + ReLU + residual; h1 out in bf16 --
__global__ __launch_bounds__(256) void k_conv1(
        const uint* __restrict__ hw2p, const int* __restrict__ cursor,
        const uint* __restrict__ recs, const int4* __restrict__ ovf,
        const int* __restrict__ ovfcnt, const float* __restrict__ dinv,
        const float* __restrict__ b, const float* __restrict__ g,
        const float* __restrict__ be, const float* __restrict__ U,
        const float* __restrict__ I, uint* __restrict__ out1) {
    int lane = threadIdx.x & 63;
    int n = __builtin_amdgcn_readfirstlane(blockIdx.x * 4 + (threadIdx.x >> 6));
    if (n >= NN) return;
    float2 a = conv_accum2(n, lane, hw2p, cursor, recs, ovf, ovfcnt);
    int p = lane & 31;
    float2 y = ln_relu2(a, dinv[n], p, b, g, be);
    const float* R = (n < NU) ? (U + (size_t)n * D) : (I + (size_t)(n - NU) * D);
    float2 rr = ((const float2*)R)[p];
    if (lane < 32) {
        out1[(size_t)n * 32 + p] =
            (uint)f2bf(y.x + rr.x) | ((uint)f2bf(y.y + rr.y) << 16);
    }
}

// --- dual-node PAIR conv accumulate for k_conv2score -------------------------
#define CB_DECL(p, c) uint p##x##c##0, p##x##c##1, p##x##c##2, p##x##c##3, \
                           p##w##c##0, p##w##c##1, p##w##c##2, p##w##c##3;
#define CB_GET(p, c, i, P, rvv) { \
    uint r = (uint)__builtin_amdgcn_ds_bpermute(vodd4 + 8 * (P), (int)(rvv)); \
    p##w##c##i = r & 0xFFFC0000u; \
    p##x##c##i = *(const uint*)((const char*)hw2p + \
                                (((r & 0x3FFFFu) << 7) + lb4)); }
#define CB_ISSUE(p, c, P0, rvv) { CB_GET(p,c,0,(P0)+0,rvv) CB_GET(p,c,1,(P0)+1,rvv) \
                                  CB_GET(p,c,2,(P0)+2,rvv) CB_GET(p,c,3,(P0)+3,rvv) }
#define CB_FMA1(p, c, i, axv, ayv) { \
    axv = fmaf(__uint_as_float(p##w##c##i), \
               __uint_as_float(p##x##c##i << 16), axv); \
    ayv = fmaf(__uint_as_float(p##w##c##i), \
               __uint_as_float(p##x##c##i & 0xFFFF0000u), ayv); }
#define CB_FMA(p, c, axv, ayv) { CB_FMA1(p,c,0,axv,ayv) CB_FMA1(p,c,1,axv,ayv) \
                                 CB_FMA1(p,c,2,axv,ayv) CB_FMA1(p,c,3,axv,ayv) }

__device__ __forceinline__ void conv_accum2_dual(int nu, int ni, int lane,
        const uint* __restrict__ hw2p, const int* __restrict__ cursor,
        const uint* __restrict__ recs, const int4* __restrict__ ovf,
        const int* __restrict__ ovfcnt, float2* outu, float2* outi) {
    int cu = __builtin_amdgcn_readfirstlane(cursor[nu]); if (cu > CAP) cu = CAP;
    int ci = __builtin_amdgcn_readfirstlane(cursor[ni]); if (ci > CAP) ci = CAP;
    uint rvu = (lane < cu) ? recs[(size_t)nu * CAP + lane] : 0u;
    uint rvi = (lane < ci) ? recs[(size_t)ni * CAP + lane] : 0u;
    const int  vodd4 = (lane >> 5) << 2;
    const uint lb4   = (uint)(lane & 31) << 2;
    uint xsu = *(const uint*)((const char*)hw2p + (((uint)nu << 7) + lb4));
    uint xsi = *(const uint*)((const char*)hw2p + (((uint)ni << 7) + lb4));
    float uax = 0.f, uay = 0.f, iax = 0.f, iay = 0.f;
    int cpu_ = (cu + 7) & ~7, cpi_ = (ci + 7) & ~7;
    CB_DECL(u, A) CB_DECL(u, B) CB_DECL(u, G)
    CB_DECL(i, A) CB_DECL(i, B) CB_DECL(i, G)
    CB_ISSUE(u, A, 0, rvu) CB_ISSUE(i, A, 0, rvi)
    CB_ISSUE(u, B, 4, rvu) CB_ISSUE(i, B, 4, rvi)
    CB_ISSUE(u, G, 8, rvu) CB_ISSUE(i, G, 8, rvi)
    CB_FMA(u, A, uax, uay) CB_FMA(i, A, iax, iay)
    if (cpu_ > 24) CB_ISSUE(u, A, 12, rvu)
    if (cpi_ > 24) CB_ISSUE(i, A, 12, rvi)
    CB_FMA(u, B, uax, uay) CB_FMA(i, B, iax, iay)
    if (cpu_ > 32) CB_ISSUE(u, B, 16, rvu)
    if (cpi_ > 32) CB_ISSUE(i, B, 16, rvi)
    CB_FMA(u, G, uax, uay) CB_FMA(i, G, iax, iay)
    if (cpu_ > 40) CB_ISSUE(u, G, 20, rvu)
    if (cpi_ > 40) CB_ISSUE(i, G, 20, rvi)
    if (cpu_ > 24) CB_FMA(u, A, uax, uay)
    if (cpi_ > 24) CB_FMA(i, A, iax, iay)
    if (cpu_ > 32) CB_FMA(u, B, uax, uay)
    if (cpi_ > 32) CB_FMA(i, B, iax, iay)
    if (cpu_ > 40) CB_FMA(u, G, uax, uay)
    if (cpi_ > 40) CB_FMA(i, G, iax, iay)
    uax += __shfl_xor(uax, 32, 64); uay += __shfl_xor(uay, 32, 64);
    iax += __shfl_xor(iax, 32, 64); iay += __shfl_xor(iay, 32, 64);
    uax += __uint_as_float(xsu << 16); uay += __uint_as_float(xsu & 0xFFFF0000u);
    iax += __uint_as_float(xsi << 16); iay += __uint_as_float(xsi & 0xFFFF0000u);
    int novf = __builtin_amdgcn_readfirstlane(ovfcnt[0]);
    if (novf > 0) {
        if (novf > OVF_MAX) novf = OVF_MAX;
        for (int j = 0; j < novf; ++j) {
            int4 e = ovf[j];
            if (e.x == nu || e.x == ni) {
                float w = __int_as_float(e.z);
                uint x = hw2p[(size_t)e.y * 32 + (lane & 31)];
                float fx = __uint_as_float(x << 16);
                float fy = __uint_as_float(x & 0xFFFF0000u);
                if (e.x == nu) { uax = fmaf(w, fx, uax); uay = fmaf(w, fy, uay); }
                else           { iax = fmaf(w, fx, iax); iay = fmaf(w, fy, iay); }
            }
        }
    }
    *outu = make_float2(uax, uay);
    *outi = make_float2(iax, iay);
}

// ------- layer-2 GEMM: hw2b = bf16((h1 @ W1) * dinv), h1 read as bf16 --------
__global__ __launch_bounds__(256) void k_gemm2(
        const ushort* __restrict__ hb, const float* __restrict__ W,
        const float* __restrict__ dinv, ushort* __restrict__ out) {
    int lane = threadIdx.x & 63;
    float wreg[64];                         // column `lane` of W1
    #pragma unroll
    for (int k = 0; k < 64; ++k) wreg[k] = W[k * 64 + lane];
    int wpb = blockDim.x >> 6;
    int wid = blockIdx.x * wpb + (threadIdx.x >> 6);
    int tw = gridDim.x * wpb;
    for (int n = wid; n < NN; n += tw) {
        float xv = __uint_as_float((uint)hb[(size_t)n * D + lane] << 16);
        float a0 = 0.f, a1 = 0.f, a2 = 0.f, a3 = 0.f;
        #pragma unroll
        for (int k = 0; k < 64; k += 4) {
            a0 = fmaf(lane_bcast(xv, k + 0), wreg[k + 0], a0);
            a1 = fmaf(lane_bcast(xv, k + 1), wreg[k + 1], a1);
            a2 = fmaf(lane_bcast(xv, k + 2), wreg[k + 2], a2);
            a3 = fmaf(lane_bcast(xv, k + 3), wreg[k + 3], a3);
        }
        out[(size_t)n * D + lane] = f2bf(((a0 + a1) + (a2 + a3)) * dinv[n]);
    }
}

// ------- FUSED layer-2 conv (sampled) + projection + scoring ------------------
__global__ __launch_bounds__(256) void k_conv2score(
        const uint* __restrict__ hw2p, const int* __restrict__ cursor,
        const uint* __restrict__ recs, const int4* __restrict__ ovf,
        const int* __restrict__ ovfcnt, const float* __restrict__ dinv,
        const float* __restrict__ b, const float* __restrict__ g,
        const float* __restrict__ be, const int* __restrict__ users,
        const int* __restrict__ items, const uint* __restrict__ h1b,
        const float* __restrict__ Wp, const float* __restrict__ bp,
        const float* __restrict__ bu, const float* __restrict__ bi,
        const float* __restrict__ mu, float* __restrict__ out, int B) {
    __shared__ float wlds[64 * 64];        // Wp, 16 KB
    int t = threadIdx.x;
    for (int i = t; i < 64 * 64; i += 256) wlds[i] = Wp[i];
    __syncthreads();
    int lane = t & 63;
    float bpl = bp[lane];
    int q = lane & 31;
    int wpb = blockDim.x >> 6;
    int wid = blockIdx.x * wpb + (t >> 6);
    int tw = gridDim.x * wpb;
    for (int p = wid; p < B; p += tw) {
        int un = users[p];
        int in_ = NU + items[p];
        int nu = __builtin_amdgcn_readfirstlane(un);
        int ni = __builtin_amdgcn_readfirstlane(in_);
        float2 au, ai;
        conv_accum2_dual(nu, ni, lane, hw2p, cursor, recs, ovf, ovfcnt,
                         &au, &ai);
        float2 yu = ln_relu2(au, dinv[nu], q, b, g, be);
        float2 yi = ln_relu2(ai, dinv[ni], q, b, g, be);
        uint xu = h1b[(size_t)nu * 32 + q];
        uint xi = h1b[(size_t)ni * 32 + q];
        float2 hu = make_float2(yu.x + __uint_as_float(xu << 16),
                                yu.y + __uint_as_float(xu & 0xFFFF0000u));
        float2 hi = make_float2(yi.x + __uint_as_float(xi << 16),
                                yi.y + __uint_as_float(xi & 0xFFFF0000u));
        // --- projection (feat 2j from .x, 2j+1 from .y) + dot
        float pu = bpl, pi = bpl;
        #pragma unroll
        for (int j = 0; j < 32; ++j) {
            float w0 = wlds[(2 * j) * 64 + lane];
            float w1 = wlds[(2 * j + 1) * 64 + lane];
            pu = fmaf(lane_bcast(hu.x, j), w0, pu);
            pu = fmaf(lane_bcast(hu.y, j), w1, pu);
            pi = fmaf(lane_bcast(hi.x, j), w0, pi);
            pi = fmaf(lane_bcast(hi.y, j), w1, pi);
        }
        float dot = pu * pi;
        #pragma unroll
        for (int m = 32; m >= 1; m >>= 1) dot += __shfl_xor(dot, m, 64);
        if (lane == 0) {
            dot += bu[un] + bi[in_ - NU] + mu[0];
            out[p] = fminf(fmaxf(dot, 1.0f), 5.0f);
        }
    }
}

extern "C" void kernel_launch(void* const* d_in, const int* in_sizes, int n_in,
                              void* d_out, int out_size, void* d_ws, size_t ws_size,
                              hipStream_t stream) {
    const int*   users = (const int*)d_in[0];
    const int*   items = (const int*)d_in[1];
    const int*   ei2   = (const int*)d_in[2];
    const float* ew    = (const float*)d_in[3];
    const float* U     = (const float*)d_in[4];
    const float* I     = (const float*)d_in[5];
    const float* W0    = (const float*)d_in[6];
    const float* b0    = (const float*)d_in[7];
    const float* g0    = (const float*)d_in[8];
    const float* be0   = (const float*)d_in[9];
    const float* W1    = (const float*)d_in[10];
    const float* b1    = (const float*)d_in[11];
    const float* g1    = (const float*)d_in[12];
    const float* be1   = (const float*)d_in[13];
    const float* Wp    = (const float*)d_in[14];
    const float* bp    = (const float*)d_in[15];
    const float* bu    = (const float*)d_in[16];
    const float* bi    = (const float*)d_in[17];
    const float* mu    = (const float*)d_in[18];

    int B = in_sizes[0];
    int E = in_sizes[2] / 2;
    const int* srcp = ei2;
    const int* dstp = ei2 + E;

    // workspace carve-up (256B aligned)
    char* p = (char*)d_ws;
    auto alloc = [&](size_t bytes) -> char* {
        char* r = p;
        p += (bytes + 255) & ~(size_t)255;
        return r;
    };
    int*    cbuf    = (int*)  alloc((size_t)(NBINS * BCPAD + 32) * 4);  // padded bincur|ovfcnt
    int*    bincur  = cbuf;                       // stride BCPAD per bin
    int*    ovfcnt  = cbuf + NBINS * BCPAD + 16;  // own cacheline
    int*    cursor  = (int*)  alloc((size_t)NN * 4);
    float*  dinv    = (float*)alloc((size_t)NN * 4);
    int4*   ovf     = (int4*) alloc((size_t)OVF_MAX * 16);
    uint2*  binbuf  = (uint2*)alloc((size_t)NBINS * BINCAP * 8); // 27.4 MB
    uint*   recs    = (uint*) alloc((size_t)NN * CAP * 4);       // 28.2 MB
    ushort* hw2b    = (ushort*)alloc((size_t)NN * D * 2);        // 19.2 MB
    uint*   h1b     = (uint*) alloc((size_t)NN * 32 * 4);        // 19.2 MB (bf16)
    const uint* hw2p = (const uint*)hw2b;
    // tail ALIASES h1b ONLY (18.0 MB <= 19.2 MB): tail is written by k_bin and
    // dead after k_regroup; h1b is first written by k_conv1 (after regroup).
    // hw2b must stay un-aliased because k_regroup's fused gemm writes it while
    // other blocks still read their tails.
    uint2*  tail    = (uint2*)h1b;   // NBINS*BIN_BLOCKS*TAILS records = 18.0 MB

    hipMemsetAsync(cbuf, 0, (size_t)(NBINS * BCPAD + 32) * 4, stream);

    int gW = (NN + 3) / 4;          // one wave per node, 4 waves/block

    // CSR build: bin -> regroup(+tails+deg+dinv+FUSED gemm1)
    k_bin<<<BIN_BLOCKS, 256, 0, stream>>>(srcp, dstp, ew, bincur, binbuf,
                                          tail, E);
    k_regroup<<<NBINS, 512, 0, stream>>>(bincur, binbuf, tail,
                                         recs, cursor, dinv, ovf, ovfcnt,
                                         U, I, W0, hw2b);

    // layer 1 conv (all nodes) -> h1 (bf16)
    k_conv1<<<gW, 256, 0, stream>>>(hw2p, cursor, recs, ovf, ovfcnt, dinv,
                                    b0, g0, be0, U, I, h1b);
    // layer 2: gemm all nodes (bf16 in), then fused sampled conv+proj+score
    k_gemm2<<<2048, 256, 0, stream>>>((const ushort*)h1b, W1, dinv, hw2b);
    k_conv2score<<<2048, 256, 0, stream>>>(hw2p, cursor, recs, ovf, ovfcnt, dinv,
                                           b1, g1, be1, users, items, h1b,
                                           Wp, bp, bu, bi, mu,
                                           (float*)d_out, B);
}

// Round 12
// 383.927 us; speedup vs baseline: 1.0667x; 1.0424x over previous
//
#include <hip/hip_runtime.h>

#define NU 100000
#define NI 50000
#define NN 150000   // NU + NI
#define D  64
#define CAP 47      // bucket capacity per dst; max in-degree ~44 for Poisson(21.3)
#define OVF_MAX 4096

// binning params (256-wide bins: regroup block reads exactly its own records)
#define BINSHIFT 8
#define BINW 256                 // dsts per bin
#define NBINS 586                // ceil(150000/256); 586*256 = 150016
#define BINCAP 5848              // per-bin record cap
#define STAGE_CAP 11             // LDS stage slots per bin (53.9KB -> 3 blocks/CU)
#define EPT 8                    // edges per thread per batch
#define BIN_BLOCKS 768           // 256 CUs x 3 blocks/CU, one round
#define BCPAD 16                 // bincur stride: 1 word per 64B cacheline
                                 // (R6-verified: removed atomic line contention)
#define TAILS 5                  // residual tail slots per bin per block
// Tail layout [bin][g][slot], count in slot0 bits [28:26] (R10/R11-verified:
// FETCH 56->34.5MB). R12: gemm1 UN-FUSED from regroup — R9's fusion ran the
// GEMM serialized on a 586-block 27%-occupancy grid (+25us) to save a ~16us
// full-occupancy dispatch. R8 evidence: both kernels separately < 74.5us.

typedef unsigned int uint;
typedef unsigned short ushort;
typedef unsigned char uchar;

// ---------------- helpers ----------------
__device__ __forceinline__ float half_reduce_add(float v) {  // reduce within 32-lane half
    #pragma unroll
    for (int m = 16; m >= 1; m >>= 1) v += __shfl_xor(v, m, 64);
    return v;
}
__device__ __forceinline__ ushort f2bf(float f) {   // round-to-nearest-even
    union { float f; uint i; } c; c.f = f;
    uint r = c.i + 0x7FFF + ((c.i >> 16) & 1);
    return (ushort)(r >> 16);
}
__device__ __forceinline__ float lane_bcast(float v, int l) {
    return __int_as_float(__builtin_amdgcn_readlane(__float_as_int(v), l));
}
// bf14 weight encoding: rounded top-14 bits of f32 (w in [0,1)); decode = 1 AND
__device__ __forceinline__ uint enc14(float w) {
    uint b = __float_as_uint(w) + 0x00020000u;   // round at bit 18
    return b & 0xFFFC0000u;
}
__device__ __forceinline__ float dec14(uint r) {
    return __uint_as_float(r & 0xFFFC0000u);
}

// ---------------- pass 1: LDS-staged binning, line-coalesced flushes ----------
// bin record: word0 = src18 | dlocal8<<18 (bits 26-31 free) ; word1 = f32 w
// Overflow (stage full / residual c>TAILS) direct-appends to binbuf (scalar
// store + cacheline-padded atomic; rare). No spill buffer.
__global__ __launch_bounds__(256) void k_bin(
        const int* __restrict__ src, const int* __restrict__ dst,
        const float* __restrict__ ew, int* __restrict__ bincur,
        uint2* __restrict__ binbuf, uint2* __restrict__ tail, int E) {
    __shared__ uint2 stage[NBINS][STAGE_CAP];   // 51.6 KB -> 3 blocks/CU
    __shared__ int scnt[NBINS];
    int t = threadIdx.x;
    for (int i = t; i < NBINS; i += 256) scnt[i] = 0;
    __syncthreads();
    const int batch = 256 * EPT;
    for (int base = blockIdx.x * batch; base < E; base += BIN_BLOCKS * batch) {
        int dd[EPT]; uint ss[EPT]; float ww[EPT]; int ok[EPT];
        #pragma unroll
        for (int k = 0; k < EPT; ++k) {
            int e = base + k * 256 + t;
            ok[k] = (e < E);
            if (ok[k]) { dd[k] = dst[e]; ss[k] = (uint)src[e]; ww[k] = ew[e]; }
        }
        #pragma unroll
        for (int k = 0; k < EPT; ++k) {
            if (!ok[k]) continue;
            int bin = dd[k] >> BINSHIFT;
            uint2 rec = make_uint2(
                ss[k] | ((uint)(dd[k] & (BINW - 1)) << 18),
                (uint)__float_as_int(ww[k]));
            int slot = atomicAdd(&scnt[bin], 1);
            if (slot < STAGE_CAP) {
                stage[bin][slot] = rec;
            } else {                      // stage full: direct-append (rare)
                int b0 = atomicAdd(&bincur[bin * BCPAD], 1);
                if (b0 < BINCAP) binbuf[(size_t)bin * BINCAP + b0] = rec;
            }
        }
        __syncthreads();
        for (int bin = t; bin < NBINS; bin += 256) {
            int c = scnt[bin]; if (c > STAGE_CAP) c = STAGE_CAP;
            while (c >= 8) {                // takes TOP 8, leaves bottom c-8
                int b0 = atomicAdd(&bincur[bin * BCPAD], 8);
                if (b0 + 8 <= BINCAP) {
                    uint4* o4 = (uint4*)(binbuf + (size_t)bin * BINCAP + b0);
                    uint2* s2 = &stage[bin][c - 8];
                    o4[0] = make_uint4(s2[0].x, s2[0].y, s2[1].x, s2[1].y);
                    o4[1] = make_uint4(s2[2].x, s2[2].y, s2[3].x, s2[3].y);
                    o4[2] = make_uint4(s2[4].x, s2[4].y, s2[5].x, s2[5].y);
                    o4[3] = make_uint4(s2[6].x, s2[6].y, s2[7].x, s2[7].y);
                }
                c -= 8;
            }
            scnt[bin] = c;
        }
        __syncthreads();
    }
    // residuals: clamp to TAILS (direct-append the excess), store clamped count
    for (int bin = t; bin < NBINS; bin += 256) {
        int c = scnt[bin]; if (c > STAGE_CAP) c = STAGE_CAP;
        if (c > TAILS) {
            for (int j = TAILS; j < c; ++j) {
                int b0 = atomicAdd(&bincur[bin * BCPAD], 1);
                if (b0 < BINCAP) binbuf[(size_t)bin * BINCAP + b0] =
                    stage[bin][j];
            }
            c = TAILS;
        }
        scnt[bin] = c;
    }
    __syncthreads();
    // transposed dump: tail[bin][g=blockIdx][slot], count in slot0 bits 26+
    for (int i = t; i < NBINS * TAILS; i += 256) {
        int bin = i / TAILS, slot = i % TAILS;
        uint2 r = stage[bin][slot];
        if (slot == 0) r.x = (r.x & 0x03FFFFFFu) | ((uint)scnt[bin] << 26);
        tail[((size_t)bin * BIN_BLOCKS + blockIdx.x) * TAILS + slot] = r;
    }
}

// -- pass 2: regroup + tails + degree + dinv (one 512-thread block per bin) ---
__global__ __launch_bounds__(512) void k_regroup(
        const int* __restrict__ bincur, const uint2* __restrict__ binbuf,
        const uint2* __restrict__ tail,
        uint* __restrict__ recs, int* __restrict__ cursor,
        float* __restrict__ dinv, int4* __restrict__ ovf,
        int* __restrict__ ovfcnt) {
    __shared__ uint image[256 * CAP];   // 47 KB, layout == recs layout
    __shared__ int cnt[256];
    __shared__ float ovfw[256];
    int t = threadIdx.x;
    int bin = blockIdx.x;
    if (t < 256) { cnt[t] = 0; ovfw[t] = 0.0f; }
    __syncthreads();
    int dbase = bin << BINSHIFT;
    int nrec = bincur[bin * BCPAD]; if (nrec > BINCAP) nrec = BINCAP;
    const uint2* bb = binbuf + (size_t)bin * BINCAP;
    // record loop with 1-deep explicit prefetch (keep a load in flight over
    // the dependent LDS-atomic+store chain)
    if (t < nrec) {
        uint2 r = bb[t];
        for (int i = t; i < nrec; ) {
            int inext = i + 512;
            uint2 rn;
            if (inext < nrec) rn = bb[inext];
            int dl = (int)(r.x >> 18);      // binbuf recs have clean top bits
            int slot = atomicAdd(&cnt[dl], 1);
            uint s = r.x & 0x3FFFFu;
            float w = __int_as_float((int)r.y);
            if (slot < CAP) image[dl * CAP + slot] = enc14(w) | s;
            else {                                          // rare high-degree
                atomicAdd(&ovfw[dl], w);
                int o = atomicAdd(ovfcnt, 1);
                if (o < OVF_MAX)
                    ovf[o] = make_int4(dbase + dl, (int)s, __float_as_int(w), 0);
            }
            i = inext; r = rn;
        }
    }
    // per-block residual tails: CONTIGUOUS stream for this bin (transposed
    // layout), count embedded in slot0 bits [28:26]
    const uint2* tbin = tail + (size_t)bin * BIN_BLOCKS * TAILS;
    for (int g = t; g < BIN_BLOCKS; g += 512) {
        const uint2* tb = tbin + (size_t)g * TAILS;
        uint2 r0 = tb[0];
        int c = (int)(r0.x >> 26);          // 0..TAILS
        r0.x &= 0x03FFFFFFu;
        for (int j = 0; j < c; ++j) {
            uint2 r = (j == 0) ? r0 : tb[j];
            int dl = (int)((r.x >> 18) & 0xFFu);
            int slot = atomicAdd(&cnt[dl], 1);
            uint s = r.x & 0x3FFFFu;
            float w = __int_as_float((int)r.y);
            if (slot < CAP) image[dl * CAP + slot] = enc14(w) | s;
            else {
                atomicAdd(&ovfw[dl], w);
                int o = atomicAdd(ovfcnt, 1);
                if (o < OVF_MAX)
                    ovf[o] = make_int4(dbase + dl, (int)s, __float_as_int(w), 0);
            }
        }
    }
    __syncthreads();
    int ndl = NN - dbase; if (ndl > 256) ndl = 256;
    if (ndl <= 0) return;
    if (t < ndl) {
        int c = cnt[t];
        cursor[dbase + t] = c;
        if (c > CAP) c = CAP;
        float dg = ovfw[t];
        for (int j = 0; j < c; ++j) dg += dec14(image[t * CAP + j]);
        dinv[dbase + t] = rsqrtf(dg + 1.0f);   // self-loop weight 1 folded in
    }
    int tot = ndl * CAP;
    uint* out = recs + (size_t)dbase * CAP;
    for (int i = t; i < tot; i += 512) out[i] = image[i];  // fully coalesced
}

// ------- layer-1 GEMM: hw2b = bf16((x @ W0) * dinv), x = [U;I] f32 -----------
__global__ __launch_bounds__(256) void k_gemm1(
        const float* __restrict__ U, const float* __restrict__ I,
        const float* __restrict__ W, const float* __restrict__ dinv,
        ushort* __restrict__ out) {
    int lane = threadIdx.x & 63;
    float wreg[64];                         // column `lane` of W0
    #pragma unroll
    for (int k = 0; k < 64; ++k) wreg[k] = W[k * 64 + lane];
    int wpb = blockDim.x >> 6;
    int wid = blockIdx.x * wpb + (threadIdx.x >> 6);
    int tw = gridDim.x * wpb;
    for (int n = wid; n < NN; n += tw) {
        float xv = (n < NU) ? U[(size_t)n * D + lane]
                            : I[(size_t)(n - NU) * D + lane];
        float a0 = 0.f, a1 = 0.f, a2 = 0.f, a3 = 0.f;  // 4 chains (ILP)
        #pragma unroll
        for (int k = 0; k < 64; k += 4) {
            a0 = fmaf(lane_bcast(xv, k + 0), wreg[k + 0], a0);
            a1 = fmaf(lane_bcast(xv, k + 1), wreg[k + 1], a1);
            a2 = fmaf(lane_bcast(xv, k + 2), wreg[k + 2], a2);
            a3 = fmaf(lane_bcast(xv, k + 3), wreg[k + 3], a3);
        }
        out[(size_t)n * D + lane] = f2bf(((a0 + a1) + (a2 + a3)) * dinv[n]);
    }
}

// --- conv accumulate (R5-verified best: 74.5us): ds_bpermute record broadcast,
//     pair layout (2 feats/lane), 12-gather BRANCH-FREE front (safe: lanes >=
//     cnt carry rv=0 -> w=0, row-0 gather), guarded pipelined tail cnt > 24. --
// hw2p = (const uint*)hw2b: row n = 32 dwords, dword p = bf16 feats (2p, 2p+1).
#define CA_DECL(c) uint x##c##0, x##c##1, x##c##2, x##c##3, \
                        w##c##0, w##c##1, w##c##2, w##c##3;
#define CA_GET(c, i, P, rvv) { \
    uint r = (uint)__builtin_amdgcn_ds_bpermute(vodd4 + 8 * (P), (int)(rvv)); \
    w##c##i = r & 0xFFFC0000u; \
    x##c##i = *(const uint*)((const char*)hw2p + \
                             (((r & 0x3FFFFu) << 7) + lb4)); }
#define CA_ISSUE(c, P0, rvv) { CA_GET(c, 0, (P0)+0, rvv) CA_GET(c, 1, (P0)+1, rvv) \
                               CA_GET(c, 2, (P0)+2, rvv) CA_GET(c, 3, (P0)+3, rvv) }
#define CA_FMA1(c, i, axv, ayv) { \
    axv = fmaf(__uint_as_float(w##c##i), __uint_as_float(x##c##i << 16), axv); \
    ayv = fmaf(__uint_as_float(w##c##i), \
               __uint_as_float(x##c##i & 0xFFFF0000u), ayv); }
#define CA_FMA(c, axv, ayv) { CA_FMA1(c,0,axv,ayv) CA_FMA1(c,1,axv,ayv) \
                              CA_FMA1(c,2,axv,ayv) CA_FMA1(c,3,axv,ayv) }

__device__ __forceinline__ float2 conv_accum2(int n, int lane,
        const uint* __restrict__ hw2p, const int* __restrict__ cursor,
        const uint* __restrict__ recs, const int4* __restrict__ ovf,
        const int* __restrict__ ovfcnt) {
    int cnt = __builtin_amdgcn_readfirstlane(cursor[n]);
    if (cnt > CAP) cnt = CAP;
    uint rv = (lane < cnt) ? recs[(size_t)n * CAP + lane] : 0u;
    const int  vodd4 = (lane >> 5) << 2;          // 0 or 4: even/odd edge half
    const uint lb4   = (uint)(lane & 31) << 2;    // byte offset within row
    uint xs = *(const uint*)((const char*)hw2p + (((uint)n << 7) + lb4));
    float ax = 0.f, ay = 0.f;
    int cp = (cnt + 7) & ~7;                      // 0..48, wave-uniform
    CA_DECL(A) CA_DECL(B) CA_DECL(G)
    // branch-free 12-deep front (covers cnt <= 24, i.e. most nodes)
    CA_ISSUE(A, 0, rv) CA_ISSUE(B, 4, rv) CA_ISSUE(G, 8, rv)
    CA_FMA(A, ax, ay)
    if (cp > 24) CA_ISSUE(A, 12, rv)
    CA_FMA(B, ax, ay)
    if (cp > 32) CA_ISSUE(B, 16, rv)
    CA_FMA(G, ax, ay)
    if (cp > 40) CA_ISSUE(G, 20, rv)
    if (cp > 24) CA_FMA(A, ax, ay)
    if (cp > 32) CA_FMA(B, ax, ay)
    if (cp > 40) CA_FMA(G, ax, ay)
    // combine even/odd halves
    ax += __shfl_xor(ax, 32, 64);
    ay += __shfl_xor(ay, 32, 64);
    // self-loop term
    ax += __uint_as_float(xs << 16);
    ay += __uint_as_float(xs & 0xFFFF0000u);
    // overflow list (normally empty)
    int novf = __builtin_amdgcn_readfirstlane(ovfcnt[0]);
    if (novf > 0) {
        if (novf > OVF_MAX) novf = OVF_MAX;
        for (int j = 0; j < novf; ++j) {
            int4 e = ovf[j];
            if (e.x == n) {
                float w = __int_as_float(e.z);
                uint x = hw2p[(size_t)e.y * 32 + (lane & 31)];
                ax = fmaf(w, __int_as_float((int)(x << 16)), ax);
                ay = fmaf(w, __int_as_float((int)(x & 0xFFFF0000u)), ay);
            }
        }
    }
    return make_float2(ax, ay);
}

// bias + LN + ReLU on pair layout; returns (y0,y1) for feats (2p, 2p+1)
__device__ __forceinline__ float2 ln_relu2(float2 a, float di, int p,
        const float* __restrict__ b, const float* __restrict__ g,
        const float* __restrict__ be) {
    float2 bb = ((const float2*)b)[p];
    float v0 = fmaf(a.x, di, bb.x);
    float v1 = fmaf(a.y, di, bb.y);
    float m = half_reduce_add(v0 + v1) * (1.0f / 64.0f);
    float d0 = v0 - m, d1 = v1 - m;
    float var = half_reduce_add(d0 * d0 + d1 * d1) * (1.0f / 64.0f);
    float rs = rsqrtf(var + 1e-5f);
    float2 gg = ((const float2*)g)[p];
    float2 ee = ((const float2*)be)[p];
    return make_float2(fmaxf(fmaf(d0 * rs, gg.x, ee.x), 0.0f),
                       fmaxf(fmaf(d1 * rs, gg.y, ee.y), 0.0f));
}

// --- layer-1 conv (all nodes) + bias + LN + ReLU + residual; h1 out in bf16 --
__global__ __launch_bounds__(256) void k_conv1(
        const uint* __restrict__ hw2p, const int* __restrict__ cursor,
        const uint* __restrict__ recs, const int4* __restrict__ ovf,
        const int* __restrict__ ovfcnt, const float* __restrict__ dinv,
        const float* __restrict__ b, const float* __restrict__ g,
        const float* __restrict__ be, const float* __restrict__ U,
        const float* __restrict__ I, uint* __restrict__ out1) {
    int lane = threadIdx.x & 63;
    int n = __builtin_amdgcn_readfirstlane(blockIdx.x * 4 + (threadIdx.x >> 6));
    if (n >= NN) return;
    float2 a = conv_accum2(n, lane, hw2p, cursor, recs, ovf, ovfcnt);
    int p = lane & 31;
    float2 y = ln_relu2(a, dinv[n], p, b, g, be);
    const float* R = (n < NU) ? (U + (size_t)n * D) : (I + (size_t)(n - NU) * D);
    float2 rr = ((const float2*)R)[p];
    if (lane < 32) {
        out1[(size_t)n * 32 + p] =
            (uint)f2bf(y.x + rr.x) | ((uint)f2bf(y.y + rr.y) << 16);
    }
}

// --- dual-node PAIR conv accumulate for k_conv2score -------------------------
#define CB_DECL(p, c) uint p##x##c##0, p##x##c##1, p##x##c##2, p##x##c##3, \
                           p##w##c##0, p##w##c##1, p##w##c##2, p##w##c##3;
#define CB_GET(p, c, i, P, rvv) { \
    uint r = (uint)__builtin_amdgcn_ds_bpermute(vodd4 + 8 * (P), (int)(rvv)); \
    p##w##c##i = r & 0xFFFC0000u; \
    p##x##c##i = *(const uint*)((const char*)hw2p + \
                                (((r & 0x3FFFFu) << 7) + lb4)); }
#define CB_ISSUE(p, c, P0, rvv) { CB_GET(p,c,0,(P0)+0,rvv) CB_GET(p,c,1,(P0)+1,rvv) \
                                  CB_GET(p,c,2,(P0)+2,rvv) CB_GET(p,c,3,(P0)+3,rvv) }
#define CB_FMA1(p, c, i, axv, ayv) { \
    axv = fmaf(__uint_as_float(p##w##c##i), \
               __uint_as_float(p##x##c##i << 16), axv); \
    ayv = fmaf(__uint_as_float(p##w##c##i), \
               __uint_as_float(p##x##c##i & 0xFFFF0000u), ayv); }
#define CB_FMA(p, c, axv, ayv) { CB_FMA1(p,c,0,axv,ayv) CB_FMA1(p,c,1,axv,ayv) \
                                 CB_FMA1(p,c,2,axv,ayv) CB_FMA1(p,c,3,axv,ayv) }

__device__ __forceinline__ void conv_accum2_dual(int nu, int ni, int lane,
        const uint* __restrict__ hw2p, const int* __restrict__ cursor,
        const uint* __restrict__ recs, const int4* __restrict__ ovf,
        const int* __restrict__ ovfcnt, float2* outu, float2* outi) {
    int cu = __builtin_amdgcn_readfirstlane(cursor[nu]); if (cu > CAP) cu = CAP;
    int ci = __builtin_amdgcn_readfirstlane(cursor[ni]); if (ci > CAP) ci = CAP;
    uint rvu = (lane < cu) ? recs[(size_t)nu * CAP + lane] : 0u;
    uint rvi = (lane < ci) ? recs[(size_t)ni * CAP + lane] : 0u;
    const int  vodd4 = (lane >> 5) << 2;
    const uint lb4   = (uint)(lane & 31) << 2;
    uint xsu = *(const uint*)((const char*)hw2p + (((uint)nu << 7) + lb4));
    uint xsi = *(const uint*)((const char*)hw2p + (((uint)ni << 7) + lb4));
    float uax = 0.f, uay = 0.f, iax = 0.f, iay = 0.f;
    int cpu_ = (cu + 7) & ~7, cpi_ = (ci + 7) & ~7;
    CB_DECL(u, A) CB_DECL(u, B) CB_DECL(u, G)
    CB_DECL(i, A) CB_DECL(i, B) CB_DECL(i, G)
    CB_ISSUE(u, A, 0, rvu) CB_ISSUE(i, A, 0, rvi)
    CB_ISSUE(u, B, 4, rvu) CB_ISSUE(i, B, 4, rvi)
    CB_ISSUE(u, G, 8, rvu) CB_ISSUE(i, G, 8, rvi)
    CB_FMA(u, A, uax, uay) CB_FMA(i, A, iax, iay)
    if (cpu_ > 24) CB_ISSUE(u, A, 12, rvu)
    if (cpi_ > 24) CB_ISSUE(i, A, 12, rvi)
    CB_FMA(u, B, uax, uay) CB_FMA(i, B, iax, iay)
    if (cpu_ > 32) CB_ISSUE(u, B, 16, rvu)
    if (cpi_ > 32) CB_ISSUE(i, B, 16, rvi)
    CB_FMA(u, G, uax, uay) CB_FMA(i, G, iax, iay)
    if (cpu_ > 40) CB_ISSUE(u, G, 20, rvu)
    if (cpi_ > 40) CB_ISSUE(i, G, 20, rvi)
    if (cpu_ > 24) CB_FMA(u, A, uax, uay)
    if (cpi_ > 24) CB_FMA(i, A, iax, iay)
    if (cpu_ > 32) CB_FMA(u, B, uax, uay)
    if (cpi_ > 32) CB_FMA(i, B, iax, iay)
    if (cpu_ > 40) CB_FMA(u, G, uax, uay)
    if (cpi_ > 40) CB_FMA(i, G, iax, iay)
    uax += __shfl_xor(uax, 32, 64); uay += __shfl_xor(uay, 32, 64);
    iax += __shfl_xor(iax, 32, 64); iay += __shfl_xor(iay, 32, 64);
    uax += __uint_as_float(xsu << 16); uay += __uint_as_float(xsu & 0xFFFF0000u);
    iax += __uint_as_float(xsi << 16); iay += __uint_as_float(xsi & 0xFFFF0000u);
    int novf = __builtin_amdgcn_readfirstlane(ovfcnt[0]);
    if (novf > 0) {
        if (novf > OVF_MAX) novf = OVF_MAX;
        for (int j = 0; j < novf; ++j) {
            int4 e = ovf[j];
            if (e.x == nu || e.x == ni) {
                float w = __int_as_float(e.z);
                uint x = hw2p[(size_t)e.y * 32 + (lane & 31)];
                float fx = __uint_as_float(x << 16);
                float fy = __uint_as_float(x & 0xFFFF0000u);
                if (e.x == nu) { uax = fmaf(w, fx, uax); uay = fmaf(w, fy, uay); }
                else           { iax = fmaf(w, fx, iax); iay = fmaf(w, fy, iay); }
            }
        }
    }
    *outu = make_float2(uax, uay);
    *outi = make_float2(iax, iay);
}

// ------- layer-2 GEMM: hw2b = bf16((h1 @ W1) * dinv), h1 read as bf16 --------
__global__ __launch_bounds__(256) void k_gemm2(
        const ushort* __restrict__ hb, const float* __restrict__ W,
        const float* __restrict__ dinv, ushort* __restrict__ out) {
    int lane = threadIdx.x & 63;
    float wreg[64];                         // column `lane` of W1
    #pragma unroll
    for (int k = 0; k < 64; ++k) wreg[k] = W[k * 64 + lane];
    int wpb = blockDim.x >> 6;
    int wid = blockIdx.x * wpb + (threadIdx.x >> 6);
    int tw = gridDim.x * wpb;
    for (int n = wid; n < NN; n += tw) {
        float xv = __uint_as_float((uint)hb[(size_t)n * D + lane] << 16);
        float a0 = 0.f, a1 = 0.f, a2 = 0.f, a3 = 0.f;
        #pragma unroll
        for (int k = 0; k < 64; k += 4) {
            a0 = fmaf(lane_bcast(xv, k + 0), wreg[k + 0], a0);
            a1 = fmaf(lane_bcast(xv, k + 1), wreg[k + 1], a1);
            a2 = fmaf(lane_bcast(xv, k + 2), wreg[k + 2], a2);
            a3 = fmaf(lane_bcast(xv, k + 3), wreg[k + 3], a3);
        }
        out[(size_t)n * D + lane] = f2bf(((a0 + a1) + (a2 + a3)) * dinv[n]);
    }
}

// ------- FUSED layer-2 conv (sampled) + projection + scoring ------------------
__global__ __launch_bounds__(256) void k_conv2score(
        const uint* __restrict__ hw2p, const int* __restrict__ cursor,
        const uint* __restrict__ recs, const int4* __restrict__ ovf,
        const int* __restrict__ ovfcnt, const float* __restrict__ dinv,
        const float* __restrict__ b, const float* __restrict__ g,
        const float* __restrict__ be, const int* __restrict__ users,
        const int* __restrict__ items, const uint* __restrict__ h1b,
        const float* __restrict__ Wp, const float* __restrict__ bp,
        const float* __restrict__ bu, const float* __restrict__ bi,
        const float* __restrict__ mu, float* __restrict__ out, int B) {
    __shared__ float wlds[64 * 64];        // Wp, 16 KB
    int t = threadIdx.x;
    for (int i = t; i < 64 * 64; i += 256) wlds[i] = Wp[i];
    __syncthreads();
    int lane = t & 63;
    float bpl = bp[lane];
    int q = lane & 31;
    int wpb = blockDim.x >> 6;
    int wid = blockIdx.x * wpb + (t >> 6);
    int tw = gridDim.x * wpb;
    for (int p = wid; p < B; p += tw) {
        int un = users[p];
        int in_ = NU + items[p];
        int nu = __builtin_amdgcn_readfirstlane(un);
        int ni = __builtin_amdgcn_readfirstlane(in_);
        float2 au, ai;
        conv_accum2_dual(nu, ni, lane, hw2p, cursor, recs, ovf, ovfcnt,
                         &au, &ai);
        float2 yu = ln_relu2(au, dinv[nu], q, b, g, be);
        float2 yi = ln_relu2(ai, dinv[ni], q, b, g, be);
        uint xu = h1b[(size_t)nu * 32 + q];
        uint xi = h1b[(size_t)ni * 32 + q];
        float2 hu = make_float2(yu.x + __uint_as_float(xu << 16),
                                yu.y + __uint_as_float(xu & 0xFFFF0000u));
        float2 hi = make_float2(yi.x + __uint_as_float(xi << 16),
                                yi.y + __uint_as_float(xi & 0xFFFF0000u));
        // --- projection (feat 2j from .x, 2j+1 from .y) + dot
        float pu = bpl, pi = bpl;
        #pragma unroll
        for (int j = 0; j < 32; ++j) {
            float w0 = wlds[(2 * j) * 64 + lane];
            float w1 = wlds[(2 * j + 1) * 64 + lane];
            pu = fmaf(lane_bcast(hu.x, j), w0, pu);
            pu = fmaf(lane_bcast(hu.y, j), w1, pu);
            pi = fmaf(lane_bcast(hi.x, j), w0, pi);
            pi = fmaf(lane_bcast(hi.y, j), w1, pi);
        }
        float dot = pu * pi;
        #pragma unroll
        for (int m = 32; m >= 1; m >>= 1) dot += __shfl_xor(dot, m, 64);
        if (lane == 0) {
            dot += bu[un] + bi[in_ - NU] + mu[0];
            out[p] = fminf(fmaxf(dot, 1.0f), 5.0f);
        }
    }
}

extern "C" void kernel_launch(void* const* d_in, const int* in_sizes, int n_in,
                              void* d_out, int out_size, void* d_ws, size_t ws_size,
                              hipStream_t stream) {
    const int*   users = (const int*)d_in[0];
    const int*   items = (const int*)d_in[1];
    const int*   ei2   = (const int*)d_in[2];
    const float* ew    = (const float*)d_in[3];
    const float* U     = (const float*)d_in[4];
    const float* I     = (const float*)d_in[5];
    const float* W0    = (const float*)d_in[6];
    const float* b0    = (const float*)d_in[7];
    const float* g0    = (const float*)d_in[8];
    const float* be0   = (const float*)d_in[9];
    const float* W1    = (const float*)d_in[10];
    const float* b1    = (const float*)d_in[11];
    const float* g1    = (const float*)d_in[12];
    const float* be1   = (const float*)d_in[13];
    const float* Wp    = (const float*)d_in[14];
    const float* bp    = (const float*)d_in[15];
    const float* bu    = (const float*)d_in[16];
    const float* bi    = (const float*)d_in[17];
    const float* mu    = (const float*)d_in[18];

    int B = in_sizes[0];
    int E = in_sizes[2] / 2;
    const int* srcp = ei2;
    const int* dstp = ei2 + E;

    // workspace carve-up (256B aligned)
    char* p = (char*)d_ws;
    auto alloc = [&](size_t bytes) -> char* {
        char* r = p;
        p += (bytes + 255) & ~(size_t)255;
        return r;
    };
    int*    cbuf    = (int*)  alloc((size_t)(NBINS * BCPAD + 32) * 4);  // padded bincur|ovfcnt
    int*    bincur  = cbuf;                       // stride BCPAD per bin
    int*    ovfcnt  = cbuf + NBINS * BCPAD + 16;  // own cacheline
    int*    cursor  = (int*)  alloc((size_t)NN * 4);
    float*  dinv    = (float*)alloc((size_t)NN * 4);
    int4*   ovf     = (int4*) alloc((size_t)OVF_MAX * 16);
    uint2*  binbuf  = (uint2*)alloc((size_t)NBINS * BINCAP * 8); // 27.4 MB
    uint*   recs    = (uint*) alloc((size_t)NN * CAP * 4);       // 28.2 MB
    ushort* hw2b    = (ushort*)alloc((size_t)NN * D * 2);        // 19.2 MB
    uint*   h1b     = (uint*) alloc((size_t)NN * 32 * 4);        // 19.2 MB (bf16)
    const uint* hw2p = (const uint*)hw2b;
    // tail ALIASES h1b ONLY (18.0 MB <= 19.2 MB): tail is written by k_bin and
    // dead after k_regroup; h1b is first written by k_conv1 (after regroup).
    uint2*  tail    = (uint2*)h1b;   // NBINS*BIN_BLOCKS*TAILS records = 18.0 MB

    hipMemsetAsync(cbuf, 0, (size_t)(NBINS * BCPAD + 32) * 4, stream);

    int gW = (NN + 3) / 4;          // one wave per node, 4 waves/block

    // CSR build: bin -> regroup(+tails+deg+dinv)
    k_bin<<<BIN_BLOCKS, 256, 0, stream>>>(srcp, dstp, ew, bincur, binbuf,
                                          tail, E);
    k_regroup<<<NBINS, 512, 0, stream>>>(bincur, binbuf, tail,
                                         recs, cursor, dinv, ovf, ovfcnt);

    // layer 1 (all nodes)
    k_gemm1<<<2048, 256, 0, stream>>>(U, I, W0, dinv, hw2b);
    k_conv1<<<gW, 256, 0, stream>>>(hw2p, cursor, recs, ovf, ovfcnt, dinv,
                                    b0, g0, be0, U, I, h1b);
    // layer 2: gemm all nodes (bf16 in), then fused sampled conv+proj+score
    k_gemm2<<<2048, 256, 0, stream>>>((const ushort*)h1b, W1, dinv, hw2b);
    k_conv2score<<<2048, 256, 0, stream>>>(hw2p, cursor, recs, ovf, ovfcnt, dinv,
                                           b1, g1, be1, users, items, h1b,
                                           Wp, bp, bu, bi, mu,
                                           (float*)d_out, B);
}